// Round 4
// baseline (2852.833 us; speedup 1.0000x reference)
//
#include <hip/hip_runtime.h>
#include <hip/hip_bf16.h>
#include <math.h>

// Problem constants
#define S31   31
#define KC    64
#define KS    7
#define KK    49          // 7*7
#define IMG   128
#define HW    16384       // 128*128
#define LAM   0.1f
#define BNEPS 1e-5f

// conv_z A-tile: plane-major LDS. 8 planes (16B ic-chunks) x 484 pixels.
#define PLSTRIDE 3872     // shorts per plane (484 * 8)

// 32x8 tiles for the direct convs (full 128-B cacheline rows)
#define TW    32
#define TH    8
#define DTW   38          // TW + 6
#define DTH   14          // TH + 6
#define DTILE 532         // DTW * DTH

typedef __attribute__((ext_vector_type(8))) short  frag8;   // 8 bf16 (4 VGPRs)
typedef __attribute__((ext_vector_type(4))) float  facc4;   // 4 fp32 acc

// fp32 -> bf16 bits, RNE
static __device__ __forceinline__ short f2bf(float f) {
    union { float f; unsigned u; } x; x.f = f;
    unsigned r = x.u + 0x7fffu + ((x.u >> 16) & 1u);
    return (short)(r >> 16);
}

// ---------------------------------------------------------------------------
// Weight reorder:
//  wz_frag[lyr][khkw][frag f=ks*4+og][lane][j] (bf16) — exact MFMA B-fragment
//    order for 16x16x32: k(=ic) = ks*32 + (lane>>4)*8 + j, n(=oc) = og*16 + (lane&15)
//  wenc_r[lyr][k][oc], wfe_r[k][oc] (fp32)
//  tail: zero pstats (BN partial-sum accumulator)
// ---------------------------------------------------------------------------
__global__ void reorder_weights(const float* __restrict__ Wz,
                                const float* __restrict__ Wenc,
                                const float* __restrict__ Wfe,
                                short* __restrict__ wz_frag,
                                float* __restrict__ wenc_r,
                                float* __restrict__ wfe_r,
                                float* __restrict__ pstats) {
    int tid = blockIdx.x * 256 + threadIdx.x;
    const int NZ = 3 * KK * 4096;         // 602112 frag elements
    const int NE = 3 * KK * KC;           // 9408
    const int NF = KK * KC;               // 3136
    const int NP = 2 * S31 * KC;          // 3968 pstats floats
    if (tid < NZ) {
        int j    = tid & 7;
        int lane = (tid >> 3) & 63;
        int og   = (tid >> 9) & 3;
        int ks   = (tid >> 11) & 1;
        int rem  = tid >> 12;            // lyr*49 + khkw
        int khkw = rem % KK;
        int lyr  = rem / KK;
        int ic = ks * 32 + ((lane >> 4) << 3) + j;
        int oc = (og << 4) + (lane & 15);
        float w = Wz[(((size_t)lyr * KC + oc) * KC + ic) * KK + khkw];
        wz_frag[tid] = f2bf(w);
    } else if (tid < NZ + NE) {
        int t = tid - NZ;
        int oc = t & 63;
        int kk = t >> 6;
        int k  = kk % KK;
        int lyr = kk / KK;
        wenc_r[t] = Wenc[((size_t)lyr * KC + oc) * KK + k];
    } else if (tid < NZ + NE + NF) {
        int t = tid - NZ - NE;
        int oc = t & 63;
        int k  = t >> 6;
        wfe_r[t] = Wfe[oc * KK + k];
    } else if (tid < NZ + NE + NF + NP) {
        pstats[tid - NZ - NE - NF] = 0.f;
    }
}

// ---------------------------------------------------------------------------
// 1 -> 64 channel conv (+optional add) + softshrink.
// 512 threads: 32x8 pixel tile (full-cacheline rows), oc split in two halves
// of 32. addsrc is prefetched into a 32-deep register array BEFORE the
// compute loop. Optionally also emits a bf16 PIXEL-MAJOR copy dst_t[s][pix][ic].
// ---------------------------------------------------------------------------
__global__ __launch_bounds__(512) void conv1to64(
        const float* __restrict__ src,    // [31, HW]
        const float* __restrict__ wr,     // [49*64] layout [k][oc]
        const float* __restrict__ bias,   // [64]
        const float* __restrict__ addsrc, // [31,64,HW] or nullptr
        float* __restrict__ dst,          // [31,64,HW]
        short* __restrict__ dst_t)        // [31,HW,64] bf16 or nullptr
{
    int s    = blockIdx.y;
    int tile = blockIdx.x;                // 4 tiles in w (32 wide), 16 in h (8 tall)
    int half = threadIdx.x >> 8;          // 0/1 -> oc 0..31 / 32..63
    int t    = threadIdx.x & 255;
    int tx = t & 31, ty = t >> 5;
    int w0 = (tile & 3) << 5, h0 = (tile >> 2) << 3;

    __shared__ float t_s[DTILE];
    const float* sp = src + (size_t)s * HW;
    for (int i = threadIdx.x; i < DTILE; i += 512) {
        int r = i / DTW, c = i - r * DTW;
        int hh = h0 - 3 + r, ww = w0 - 3 + c;
        t_s[i] = (hh >= 0 && hh < IMG && ww >= 0 && ww < IMG) ? sp[hh * IMG + ww] : 0.f;
    }
    __syncthreads();

    int pix = (h0 + ty) * IMG + (w0 + tx);
    size_t base = ((size_t)s * KC + half * 32) * HW + pix;

    // 32-deep prefetch of addsrc (issued before the compute loop, kept live)
    float addv[32];
    if (addsrc) {
#pragma unroll
        for (int i = 0; i < 32; i++) addv[i] = addsrc[base + (size_t)i * HW];
    } else {
#pragma unroll
        for (int i = 0; i < 32; i++) addv[i] = 0.f;
    }
    __builtin_amdgcn_sched_barrier(0);   // keep the loads issued up here

    float acc[32];
#pragma unroll
    for (int i = 0; i < 32; i++) acc[i] = 0.f;

    const float* wrh = wr + half * 32;
#pragma unroll 1
    for (int kh = 0; kh < KS; kh++) {
#pragma unroll
        for (int kw = 0; kw < KS; kw++) {
            float v = t_s[(ty + kh) * DTW + tx + kw];
            const float* wk = wrh + (kh * KS + kw) * KC;
#pragma unroll
            for (int i = 0; i < 32; i++) acc[i] += v * wk[i];
        }
    }

#pragma unroll
    for (int g = 0; g < 4; g++) {
        frag8 vv;
#pragma unroll
        for (int j = 0; j < 8; j++) {
            int i = g * 8 + j;
            float v = acc[i] + bias[half * 32 + i];   // same assoc order as R2
            v += addv[i];                             // (+0.0f when no addsrc)
            v = (v > LAM) ? (v - LAM) : ((v < -LAM) ? (v + LAM) : 0.f);
            dst[base + (size_t)i * HW] = v;
            vv[j] = f2bf(v);
        }
        if (dst_t) {
            *(frag8*)(dst_t + ((size_t)s * HW + pix) * KC + half * 32 + g * 8) = vv;
        }
    }
}

// ---------------------------------------------------------------------------
// 64 -> 1 channel conv. If xsub != null, out = xsub - (conv+b); else conv+b.
// 32x8 tile; ic staged 4 planes/round, double-buffered LDS with register
// prefetch. Accumulation order (ic asc, kh, kw) identical -> bit-exact.
// ---------------------------------------------------------------------------
#define ICB   4
#define CHUNK (ICB * DTILE)   // 2128

__global__ __launch_bounds__(256) void conv64to1(
        const float* __restrict__ src,   // [31,64,HW]
        const float* __restrict__ w,     // [64*49] layout [ic][k]
        const float* __restrict__ bias,  // [1]
        const float* __restrict__ xsub,  // [31,HW] or nullptr
        float* __restrict__ dst)         // [31,HW]
{
    int s    = blockIdx.y;
    int tile = blockIdx.x;
    int tx = threadIdx.x & 31, ty = threadIdx.x >> 5;
    int w0 = (tile & 3) << 5, h0 = (tile >> 2) << 3;

    __shared__ float t_s[2][CHUNK];      // 17 KB

    // per-thread load slots: identical pattern every chunk, precompute once
    int  goff[9];
    bool okf[9];
#pragma unroll
    for (int r = 0; r < 9; r++) {
        int j = threadIdx.x + r * 256;
        if (j < CHUNK) {
            int plane = j / DTILE, p = j - plane * DTILE;
            int rr = p / DTW, cc = p - rr * DTW;
            int hh = h0 - 3 + rr, ww = w0 - 3 + cc;
            bool inb = (hh >= 0 && hh < IMG && ww >= 0 && ww < IMG);
            goff[r] = plane * HW + (inb ? (hh * IMG + ww) : 0);
            okf[r]  = inb;
        }
    }

    const float* sbase = src + (size_t)s * KC * HW;

    // stage chunk 0
    float ldv[9];
#pragma unroll
    for (int r = 0; r < 9; r++)
        if (threadIdx.x + r * 256 < CHUNK)
            ldv[r] = okf[r] ? sbase[goff[r]] : 0.f;
#pragma unroll
    for (int r = 0; r < 9; r++)
        if (threadIdx.x + r * 256 < CHUNK)
            t_s[0][threadIdx.x + r * 256] = ldv[r];

    float acc = 0.f;
    __syncthreads();

#pragma unroll 1
    for (int blk = 0; blk < 16; blk++) {
        int cur = blk & 1;
        // prefetch next chunk into regs (overlaps the compute below)
        if (blk < 15) {
            const float* nb = sbase + (size_t)(blk + 1) * ICB * HW;
#pragma unroll
            for (int r = 0; r < 9; r++)
                if (threadIdx.x + r * 256 < CHUNK)
                    ldv[r] = okf[r] ? nb[goff[r]] : 0.f;
        }
        __builtin_amdgcn_sched_barrier(0);
        // compute 4 planes of this chunk
#pragma unroll
        for (int pl = 0; pl < ICB; pl++) {
            int ic = blk * ICB + pl;
            const float* wk = w + ic * KK;
            const float* ts = &t_s[cur][pl * DTILE];
#pragma unroll 1
            for (int kh = 0; kh < KS; kh++) {
#pragma unroll
                for (int kw = 0; kw < KS; kw++)
                    acc += ts[(ty + kh) * DTW + tx + kw] * wk[kh * KS + kw];
            }
        }
        __syncthreads();
        if (blk < 15) {
#pragma unroll
            for (int r = 0; r < 9; r++)
                if (threadIdx.x + r * 256 < CHUNK)
                    t_s[cur ^ 1][threadIdx.x + r * 256] = ldv[r];
            __syncthreads();
        }
    }

    float v = acc + bias[0];
    int pix = (h0 + ty) * IMG + (w0 + tx);
    if (xsub) v = xsub[(size_t)s * HW + pix] - v;
    dst[(size_t)s * HW + pix] = v;
}

// ---------------------------------------------------------------------------
// conv_z as bf16 MFMA shift-GEMM: zpre[s][oc][px] = sum_{ic,kh,kw} ...
// Block: 256 thr (4 waves) = 16x16 pixel tile x 64 oc, all 49 taps, K=64 ic.
// A tile: PLANE-MAJOR LDS: 8 planes (one per 16B ic-chunk) x 484 pixels,
//   plane stride 7744 B. Each lane's plane (cq = ks*4+q) is a lane CONSTANT,
//   so bank group = (pixel + 4*(q&1)) mod 8 -> uniform 8 lanes/group:
//   conflict-free reads AND writes (was ~4 extra cyc/read at stride 144 B).
// Tap loop FULLY UNROLLED: all 49x8 A-reads are immediate-offset ds_read_b128
//   off ONE per-lane base (max offset 34 KB < 64 KB imm) — kills the per-tap
//   runtime div + address VALU (was ~29% VALUBusy).
// B taps: direct-from-global register double-buffer, zero barriers in K-loop.
// Epilogue: fused BN partial sums via q-lane shfl + atomicAdd.
// ---------------------------------------------------------------------------
__global__ __launch_bounds__(256) void conv_z_mfma(
        const short* __restrict__ srcT,  // [31,HW,64] bf16 (tmp_t)
        const short* __restrict__ wfrag, // per-layer B-frag buffer (bf16 bits)
        const float* __restrict__ bias,  // [64]
        float* __restrict__ dst,         // [31,64,HW] (zpre)
        float* __restrict__ pstats)      // [31*64][2] partial sums (pre-zeroed)
{
    __shared__ __align__(16) short a_s[8 * PLSTRIDE]; // 61,952 B

    int s    = blockIdx.y;
    int tile = blockIdx.x;
    int h0 = (tile >> 3) << 4, w0 = (tile & 7) << 4;
    int tid  = threadIdx.x;
    int wave = tid >> 6, lane = tid & 63;
    int q = lane >> 4, m = lane & 15;

    // ---- stage A: bf16 [pix][ic] -> plane-major LDS; all b128, conflict-free
    const short* tsrc = srcT + (size_t)s * HW * KC;
#pragma unroll
    for (int rep = 0; rep < 2; rep++) {
        int p = tid + rep * 256;
        if (p < 484) {
            int r = p / 22, c = p - r * 22;
            int hh = h0 - 3 + r, ww = w0 - 3 + c;
            bool ok = (hh >= 0 && hh < IMG && ww >= 0 && ww < IMG);
            const short* px = tsrc + ((size_t)(ok ? (hh * IMG + ww) : 0) << 6);
            short* dp = a_s + p * 8;
#pragma unroll
            for (int c8 = 0; c8 < 8; c8++) {
                frag8 v;
                if (ok) v = *(const frag8*)(px + (c8 << 3));
                else    v = (frag8)(short)0;
                *(frag8*)(dp + c8 * PLSTRIDE) = v;
            }
        }
    }

    facc4 acc[4][4];
#pragma unroll
    for (int i = 0; i < 4; i++)
#pragma unroll
        for (int j = 0; j < 4; j++)
            acc[i][j] = (facc4){0.f, 0.f, 0.f, 0.f};

    __syncthreads();   // a_s ready; read-only from here: no more barriers

    // per-lane A base: plane q (ks=0 part), pixel (wave*4*22 + m).
    // read offsets: ks*4*PLSTRIDE + ((kh+pg)*22 + kw)*8  — all compile-time.
    const short* abase = a_s + q * PLSTRIDE + (wave * 4 * 22 + m) * 8;

#define AFRAG(pg, ks, kh, kw) \
    (*(const frag8*)(abase + (ks) * (4 * PLSTRIDE) + (((kh) + (pg)) * 22 + (kw)) * 8))

    // B frag load: tap block is 4096 bf16 = [frag f][lane][8j]
#define LOADB(dstb, tap) do {                                                  \
        const frag8* bp = (const frag8*)(wfrag + ((tap) << 12));               \
        _Pragma("unroll")                                                      \
        for (int f = 0; f < 8; f++) dstb[f] = bp[(f << 6) + lane];             \
    } while (0)

#define COMPUTE(tap, b) do {                                                   \
        const int kh = (tap) / 7, kw = (tap) - kh * 7;                         \
        _Pragma("unroll")                                                      \
        for (int ks = 0; ks < 2; ks++) {                                       \
            frag8 a0 = AFRAG(0, ks, kh, kw);                                   \
            frag8 a1 = AFRAG(1, ks, kh, kw);                                   \
            frag8 a2 = AFRAG(2, ks, kh, kw);                                   \
            frag8 a3 = AFRAG(3, ks, kh, kw);                                   \
            acc[0][0] = __builtin_amdgcn_mfma_f32_16x16x32_bf16(a0, b[ks*4+0], acc[0][0], 0, 0, 0); \
            acc[0][1] = __builtin_amdgcn_mfma_f32_16x16x32_bf16(a0, b[ks*4+1], acc[0][1], 0, 0, 0); \
            acc[0][2] = __builtin_amdgcn_mfma_f32_16x16x32_bf16(a0, b[ks*4+2], acc[0][2], 0, 0, 0); \
            acc[0][3] = __builtin_amdgcn_mfma_f32_16x16x32_bf16(a0, b[ks*4+3], acc[0][3], 0, 0, 0); \
            acc[1][0] = __builtin_amdgcn_mfma_f32_16x16x32_bf16(a1, b[ks*4+0], acc[1][0], 0, 0, 0); \
            acc[1][1] = __builtin_amdgcn_mfma_f32_16x16x32_bf16(a1, b[ks*4+1], acc[1][1], 0, 0, 0); \
            acc[1][2] = __builtin_amdgcn_mfma_f32_16x16x32_bf16(a1, b[ks*4+2], acc[1][2], 0, 0, 0); \
            acc[1][3] = __builtin_amdgcn_mfma_f32_16x16x32_bf16(a1, b[ks*4+3], acc[1][3], 0, 0, 0); \
            acc[2][0] = __builtin_amdgcn_mfma_f32_16x16x32_bf16(a2, b[ks*4+0], acc[2][0], 0, 0, 0); \
            acc[2][1] = __builtin_amdgcn_mfma_f32_16x16x32_bf16(a2, b[ks*4+1], acc[2][1], 0, 0, 0); \
            acc[2][2] = __builtin_amdgcn_mfma_f32_16x16x32_bf16(a2, b[ks*4+2], acc[2][2], 0, 0, 0); \
            acc[2][3] = __builtin_amdgcn_mfma_f32_16x16x32_bf16(a2, b[ks*4+3], acc[2][3], 0, 0, 0); \
            acc[3][0] = __builtin_amdgcn_mfma_f32_16x16x32_bf16(a3, b[ks*4+0], acc[3][0], 0, 0, 0); \
            acc[3][1] = __builtin_amdgcn_mfma_f32_16x16x32_bf16(a3, b[ks*4+1], acc[3][1], 0, 0, 0); \
            acc[3][2] = __builtin_amdgcn_mfma_f32_16x16x32_bf16(a3, b[ks*4+2], acc[3][2], 0, 0, 0); \
            acc[3][3] = __builtin_amdgcn_mfma_f32_16x16x32_bf16(a3, b[ks*4+3], acc[3][3], 0, 0, 0); \
        }                                                                      \
    } while (0)

    frag8 bA[8], bB[8];
    LOADB(bA, 0);
    // straight-line software pipeline: tap indices are LITERAL constants ->
    // every ds_read is base+immediate, every B pointer folds to SGPR math.
#define STEP2(t) LOADB(bB, (t)+1); COMPUTE((t), bA); \
                 LOADB(bA, (t)+2); COMPUTE((t)+1, bB);
    STEP2(0)  STEP2(2)  STEP2(4)  STEP2(6)  STEP2(8)  STEP2(10)
    STEP2(12) STEP2(14) STEP2(16) STEP2(18) STEP2(20) STEP2(22)
    STEP2(24) STEP2(26) STEP2(28) STEP2(30) STEP2(32) STEP2(34)
    STEP2(36) STEP2(38) STEP2(40) STEP2(42) STEP2(44) STEP2(46)
    COMPUTE(48, bA);
#undef STEP2
#undef LOADB
#undef COMPUTE
#undef AFRAG

    // ---- epilogue: D layout col(oc-part)=lane&15, row(px col)=q*4+reg
    //      + fused BN partial sums (per oc: reduce over q-lanes, atomicAdd)
    int prow = h0 + wave * 4;
#pragma unroll
    for (int og = 0; og < 4; og++) {
        int oc = og * 16 + m;
        float bb = bias[oc];
        float s1 = 0.f, s2 = 0.f;
#pragma unroll
        for (int pg = 0; pg < 4; pg++) {
            float* dp = dst + ((size_t)s * KC + oc) * HW
                            + (size_t)(prow + pg) * IMG + w0 + q * 4;
            float4 v;
            v.x = acc[pg][og][0] + bb;
            v.y = acc[pg][og][1] + bb;
            v.z = acc[pg][og][2] + bb;
            v.w = acc[pg][og][3] + bb;
            s1 += v.x + v.y + v.z + v.w;
            s2 += v.x * v.x + v.y * v.y + v.z * v.z + v.w * v.w;
            *(float4*)dp = v;
        }
        // reduce over the 4 q-lanes sharing this oc (lane bits 4,5)
        s1 += __shfl_xor(s1, 16, 64); s2 += __shfl_xor(s2, 16, 64);
        s1 += __shfl_xor(s1, 32, 64); s2 += __shfl_xor(s2, 32, 64);
        if (q == 0) {
            atomicAdd(&pstats[(s * KC + oc) * 2],     s1);
            atomicAdd(&pstats[(s * KC + oc) * 2 + 1], s2);
        }
    }
}

// ---------------------------------------------------------------------------
// Finalize BN stats from fused partial sums; re-zero pstats for next iter.
// ---------------------------------------------------------------------------
__global__ __launch_bounds__(64) void bn_finalize(
        float* __restrict__ pstats,   // [31*64][2] partial sums
        float* __restrict__ stats)    // [31*64][2] -> (mu, rsqrt(var+eps))
{
    int i = blockIdx.x * 64 + threadIdx.x;
    if (i < S31 * KC) {
        float s1 = pstats[i * 2], s2 = pstats[i * 2 + 1];
        pstats[i * 2] = 0.f;
        pstats[i * 2 + 1] = 0.f;
        float mu  = s1 * (1.f / HW);
        float var = s2 * (1.f / HW) - mu * mu;
        if (var < 0.f) var = 0.f;
        stats[i * 2]     = mu;
        stats[i * 2 + 1] = rsqrtf(var + BNEPS);
    }
}

// ---------------------------------------------------------------------------
// Directional gated band scan: each thread owns one (c,h,w), walks 31 bands.
// ---------------------------------------------------------------------------
__global__ __launch_bounds__(256) void band_scan(
        const float* __restrict__ tmp,   // [31,64,HW]
        const float* __restrict__ zpre,  // [31,64,HW]
        const float* __restrict__ stats, // [31*64][2]
        const float* __restrict__ gamma, // [64]
        const float* __restrict__ beta,  // [64]
        float* __restrict__ csc,         // [31,64,HW]
        int fwd)
{
    int idx = blockIdx.x * 256 + threadIdx.x;  // 0 .. 64*HW-1
    int c = idx >> 14;
    float g = gamma[c], be = beta[c];
    float prev = 0.f;
    for (int step = 0; step < S31; step++) {
        int s = fwd ? step : (S31 - 1 - step);
        size_t off = (size_t)s * KC * HW + idx;
        float t  = tmp[off];
        float zp = zpre[off];
        float mu = stats[(s * KC + c) * 2];
        float rs = stats[(s * KC + c) * 2 + 1];
        float zn = (zp - mu) * rs * g + be;
        float z  = 1.f / (1.f + expf(-zn));
        float cur = (step == 0) ? t : (z * prev + (1.f - z) * t);
        csc[off] = cur;
        prev = cur;
    }
}

// ---------------------------------------------------------------------------
extern "C" void kernel_launch(void* const* d_in, const int* in_sizes, int n_in,
                              void* d_out, int out_size, void* d_ws, size_t ws_size,
                              hipStream_t stream) {
    const float* x      = (const float*)d_in[0];   // [1,31,128,128]
    const float* W_fe   = (const float*)d_in[1];
    const float* b_fe   = (const float*)d_in[2];
    const float* W_enc  = (const float*)d_in[3];
    const float* b_enc  = (const float*)d_in[4];
    const float* W_dec  = (const float*)d_in[5];
    const float* b_dec  = (const float*)d_in[6];
    const float* W_last = (const float*)d_in[7];
    const float* b_last = (const float*)d_in[8];
    const float* W_z    = (const float*)d_in[9];
    const float* b_z    = (const float*)d_in[10];
    const float* bn_g   = (const float*)d_in[11];
    const float* bn_b   = (const float*)d_in[12];

    float* out     = (float*)d_out;
    float* csc     = out;                               // [31,1,64,128,128]
    float* outputs = out + (size_t)S31 * KC * HW;       // [1,31,128,128]

    char* ws = (char*)d_ws;
    float* tmp     = (float*)ws; ws += (size_t)S31 * KC * HW * 4;
    float* zpre    = (float*)ws; ws += (size_t)S31 * KC * HW * 4;
    float* res     = (float*)ws; ws += (size_t)S31 * HW * 4;
    float* stats   = (float*)ws; ws += (size_t)S31 * KC * 2 * 4;
    float* pstats  = (float*)ws; ws += (size_t)S31 * KC * 2 * 4;
    short* wz_frag = (short*)ws; ws += (size_t)3 * KK * 4096 * 2;  // bf16 frags
    float* wenc_r  = (float*)ws; ws += (size_t)3 * KK * KC * 4;
    float* wfe_r   = (float*)ws; ws += (size_t)KK * KC * 4;
    short* tmp_t   = (short*)ws; ws += (size_t)S31 * HW * KC * 2;  // bf16 pix-major

    // 1) weight reorder / frag-swizzle (+ zero pstats)
    {
        int total = 3 * KK * 4096 + 3 * KK * KC + KK * KC + 2 * S31 * KC;
        reorder_weights<<<(total + 255) / 256, 256, 0, stream>>>(
            W_z, W_enc, W_fe, wz_frag, wenc_r, wfe_r, pstats);
    }

    dim3 gconv(64, S31);

    // 2) csc = softshrink(conv_fe(x))
    conv1to64<<<gconv, 512, 0, stream>>>(x, wfe_r, b_fe, nullptr, csc, nullptr);

    for (int it = 0; it < 3; it++) {
        int lyr = it;
        // res = x - (conv_dec(csc) + b_dec)
        conv64to1<<<gconv, 256, 0, stream>>>(
            csc, W_dec + (size_t)lyr * KC * KK, b_dec + lyr, x, res);
        // tmp = softshrink(csc + conv_enc(res) + b_enc)  (+ bf16 pix-major copy)
        conv1to64<<<gconv, 512, 0, stream>>>(
            res, wenc_r + (size_t)lyr * KK * KC, b_enc + (size_t)lyr * KC, csc,
            tmp, tmp_t);
        // zpre = conv_z(tmp) + b_z   (bf16 MFMA shift-GEMM, plane-major LDS,
        //                             fully-unrolled tap pipeline, fused BN)
        conv_z_mfma<<<gconv, 256, 0, stream>>>(
            tmp_t, wz_frag + (size_t)lyr * KK * 4096, b_z + (size_t)lyr * KC,
            zpre, pstats);
        // BN finalize (also re-zeroes pstats for the next iteration)
        bn_finalize<<<S31, 64, 0, stream>>>(pstats, stats);
        // gated directional scan -> csc
        band_scan<<<(KC * HW) / 256, 256, 0, stream>>>(
            tmp, zpre, stats, bn_g + (size_t)lyr * KC, bn_b + (size_t)lyr * KC,
            csc, (it % 2 == 0) ? 1 : 0);
    }

    // 3) outputs = conv_last(csc) + b_last
    conv64to1<<<gconv, 256, 0, stream>>>(csc, W_last, b_last, nullptr, outputs);
}

// Round 5
// 2513.033 us; speedup vs baseline: 1.1352x; 1.1352x over previous
//
#include <hip/hip_runtime.h>
#include <hip/hip_bf16.h>
#include <math.h>

// Problem constants
#define S31   31
#define KC    64
#define KS    7
#define KK    49          // 7*7
#define IMG   128
#define HW    16384       // 128*128
#define LAM   0.1f
#define BNEPS 1e-5f

// conv_z A-tile: plane-major LDS. 8 planes (16B ic-chunks) x 484 pixels.
#define PLSTRIDE 3872     // shorts per plane (484 * 8)

// 32x8 tiles for the direct convs (full 128-B cacheline rows)
#define TW    32
#define TH    8
#define DTW   38          // TW + 6
#define DTH   14          // TH + 6
#define DTILE 532         // DTW * DTH

typedef __attribute__((ext_vector_type(8))) short  frag8;   // 8 bf16 (4 VGPRs)
typedef __attribute__((ext_vector_type(4))) float  facc4;   // 4 fp32 acc

// fp32 -> bf16 bits, RNE
static __device__ __forceinline__ short f2bf(float f) {
    union { float f; unsigned u; } x; x.f = f;
    unsigned r = x.u + 0x7fffu + ((x.u >> 16) & 1u);
    return (short)(r >> 16);
}

// ---------------------------------------------------------------------------
// Weight reorder:
//  wz_frag[lyr][khkw][frag f=ks*4+og][lane][j] (bf16) — exact MFMA B-fragment
//    order for 16x16x32: k(=ic) = ks*32 + (lane>>4)*8 + j, n(=oc) = og*16 + (lane&15)
//  wenc_r[lyr][k][oc], wfe_r[k][oc] (fp32)
//  tail: zero pstats (BN partial-sum accumulator)
// ---------------------------------------------------------------------------
__global__ void reorder_weights(const float* __restrict__ Wz,
                                const float* __restrict__ Wenc,
                                const float* __restrict__ Wfe,
                                short* __restrict__ wz_frag,
                                float* __restrict__ wenc_r,
                                float* __restrict__ wfe_r,
                                float* __restrict__ pstats) {
    int tid = blockIdx.x * 256 + threadIdx.x;
    const int NZ = 3 * KK * 4096;         // 602112 frag elements
    const int NE = 3 * KK * KC;           // 9408
    const int NF = KK * KC;               // 3136
    const int NP = 2 * S31 * KC;          // 3968 pstats floats
    if (tid < NZ) {
        int j    = tid & 7;
        int lane = (tid >> 3) & 63;
        int og   = (tid >> 9) & 3;
        int ks   = (tid >> 11) & 1;
        int rem  = tid >> 12;            // lyr*49 + khkw
        int khkw = rem % KK;
        int lyr  = rem / KK;
        int ic = ks * 32 + ((lane >> 4) << 3) + j;
        int oc = (og << 4) + (lane & 15);
        float w = Wz[(((size_t)lyr * KC + oc) * KC + ic) * KK + khkw];
        wz_frag[tid] = f2bf(w);
    } else if (tid < NZ + NE) {
        int t = tid - NZ;
        int oc = t & 63;
        int kk = t >> 6;
        int k  = kk % KK;
        int lyr = kk / KK;
        wenc_r[t] = Wenc[((size_t)lyr * KC + oc) * KK + k];
    } else if (tid < NZ + NE + NF) {
        int t = tid - NZ - NE;
        int oc = t & 63;
        int k  = t >> 6;
        wfe_r[t] = Wfe[oc * KK + k];
    } else if (tid < NZ + NE + NF + NP) {
        pstats[tid - NZ - NE - NF] = 0.f;
    }
}

// ---------------------------------------------------------------------------
// 1 -> 64 channel conv (+optional add) + softshrink.
// 512 threads: 32x8 pixel tile (full-cacheline rows), oc split in two halves
// of 32. addsrc is prefetched into a 32-deep register array BEFORE the
// compute loop. Optionally also emits a bf16 PIXEL-MAJOR copy dst_t[s][pix][ic].
// ---------------------------------------------------------------------------
__global__ __launch_bounds__(512) void conv1to64(
        const float* __restrict__ src,    // [31, HW]
        const float* __restrict__ wr,     // [49*64] layout [k][oc]
        const float* __restrict__ bias,   // [64]
        const float* __restrict__ addsrc, // [31,64,HW] or nullptr
        float* __restrict__ dst,          // [31,64,HW]
        short* __restrict__ dst_t)        // [31,HW,64] bf16 or nullptr
{
    int s    = blockIdx.y;
    int tile = blockIdx.x;                // 4 tiles in w (32 wide), 16 in h (8 tall)
    int half = threadIdx.x >> 8;          // 0/1 -> oc 0..31 / 32..63
    int t    = threadIdx.x & 255;
    int tx = t & 31, ty = t >> 5;
    int w0 = (tile & 3) << 5, h0 = (tile >> 2) << 3;

    __shared__ float t_s[DTILE];
    const float* sp = src + (size_t)s * HW;
    for (int i = threadIdx.x; i < DTILE; i += 512) {
        int r = i / DTW, c = i - r * DTW;
        int hh = h0 - 3 + r, ww = w0 - 3 + c;
        t_s[i] = (hh >= 0 && hh < IMG && ww >= 0 && ww < IMG) ? sp[hh * IMG + ww] : 0.f;
    }
    __syncthreads();

    int pix = (h0 + ty) * IMG + (w0 + tx);
    size_t base = ((size_t)s * KC + half * 32) * HW + pix;

    // 32-deep prefetch of addsrc (issued before the compute loop, kept live)
    float addv[32];
    if (addsrc) {
#pragma unroll
        for (int i = 0; i < 32; i++) addv[i] = addsrc[base + (size_t)i * HW];
    } else {
#pragma unroll
        for (int i = 0; i < 32; i++) addv[i] = 0.f;
    }
    __builtin_amdgcn_sched_barrier(0);   // keep the loads issued up here

    float acc[32];
#pragma unroll
    for (int i = 0; i < 32; i++) acc[i] = 0.f;

    const float* wrh = wr + half * 32;
#pragma unroll 1
    for (int kh = 0; kh < KS; kh++) {
#pragma unroll
        for (int kw = 0; kw < KS; kw++) {
            float v = t_s[(ty + kh) * DTW + tx + kw];
            const float* wk = wrh + (kh * KS + kw) * KC;
#pragma unroll
            for (int i = 0; i < 32; i++) acc[i] += v * wk[i];
        }
    }

#pragma unroll
    for (int g = 0; g < 4; g++) {
        frag8 vv;
#pragma unroll
        for (int j = 0; j < 8; j++) {
            int i = g * 8 + j;
            float v = acc[i] + bias[half * 32 + i];   // same assoc order as R2
            v += addv[i];                             // (+0.0f when no addsrc)
            v = (v > LAM) ? (v - LAM) : ((v < -LAM) ? (v + LAM) : 0.f);
            dst[base + (size_t)i * HW] = v;
            vv[j] = f2bf(v);
        }
        if (dst_t) {
            *(frag8*)(dst_t + ((size_t)s * HW + pix) * KC + half * 32 + g * 8) = vv;
        }
    }
}

// ---------------------------------------------------------------------------
// 64 -> 1 channel conv. If xsub != null, out = xsub - (conv+b); else conv+b.
// 32x8 tile; ic staged 4 planes/round, double-buffered LDS with register
// prefetch. Accumulation order (ic asc, kh, kw) identical -> bit-exact.
// ---------------------------------------------------------------------------
#define ICB   4
#define CHUNK (ICB * DTILE)   // 2128

__global__ __launch_bounds__(256) void conv64to1(
        const float* __restrict__ src,   // [31,64,HW]
        const float* __restrict__ w,     // [64*49] layout [ic][k]
        const float* __restrict__ bias,  // [1]
        const float* __restrict__ xsub,  // [31,HW] or nullptr
        float* __restrict__ dst)         // [31,HW]
{
    int s    = blockIdx.y;
    int tile = blockIdx.x;
    int tx = threadIdx.x & 31, ty = threadIdx.x >> 5;
    int w0 = (tile & 3) << 5, h0 = (tile >> 2) << 3;

    __shared__ float t_s[2][CHUNK];      // 17 KB

    // per-thread load slots: identical pattern every chunk, precompute once
    int  goff[9];
    bool okf[9];
#pragma unroll
    for (int r = 0; r < 9; r++) {
        int j = threadIdx.x + r * 256;
        if (j < CHUNK) {
            int plane = j / DTILE, p = j - plane * DTILE;
            int rr = p / DTW, cc = p - rr * DTW;
            int hh = h0 - 3 + rr, ww = w0 - 3 + cc;
            bool inb = (hh >= 0 && hh < IMG && ww >= 0 && ww < IMG);
            goff[r] = plane * HW + (inb ? (hh * IMG + ww) : 0);
            okf[r]  = inb;
        }
    }

    const float* sbase = src + (size_t)s * KC * HW;

    // stage chunk 0
    float ldv[9];
#pragma unroll
    for (int r = 0; r < 9; r++)
        if (threadIdx.x + r * 256 < CHUNK)
            ldv[r] = okf[r] ? sbase[goff[r]] : 0.f;
#pragma unroll
    for (int r = 0; r < 9; r++)
        if (threadIdx.x + r * 256 < CHUNK)
            t_s[0][threadIdx.x + r * 256] = ldv[r];

    float acc = 0.f;
    __syncthreads();

#pragma unroll 1
    for (int blk = 0; blk < 16; blk++) {
        int cur = blk & 1;
        // prefetch next chunk into regs (overlaps the compute below)
        if (blk < 15) {
            const float* nb = sbase + (size_t)(blk + 1) * ICB * HW;
#pragma unroll
            for (int r = 0; r < 9; r++)
                if (threadIdx.x + r * 256 < CHUNK)
                    ldv[r] = okf[r] ? nb[goff[r]] : 0.f;
        }
        __builtin_amdgcn_sched_barrier(0);
        // compute 4 planes of this chunk
#pragma unroll
        for (int pl = 0; pl < ICB; pl++) {
            int ic = blk * ICB + pl;
            const float* wk = w + ic * KK;
            const float* ts = &t_s[cur][pl * DTILE];
#pragma unroll 1
            for (int kh = 0; kh < KS; kh++) {
#pragma unroll
                for (int kw = 0; kw < KS; kw++)
                    acc += ts[(ty + kh) * DTW + tx + kw] * wk[kh * KS + kw];
            }
        }
        __syncthreads();
        if (blk < 15) {
#pragma unroll
            for (int r = 0; r < 9; r++)
                if (threadIdx.x + r * 256 < CHUNK)
                    t_s[cur ^ 1][threadIdx.x + r * 256] = ldv[r];
            __syncthreads();
        }
    }

    float v = acc + bias[0];
    int pix = (h0 + ty) * IMG + (w0 + tx);
    if (xsub) v = xsub[(size_t)s * HW + pix] - v;
    dst[(size_t)s * HW + pix] = v;
}

// ---------------------------------------------------------------------------
// conv_z as bf16 MFMA shift-GEMM: zpre[s][oc][px] = sum_{ic,kh,kw} ...
// Block: 256 thr (4 waves) = 16x16 pixel tile x 64 oc, all 49 taps, K=64 ic.
// A tile: PLANE-MAJOR LDS (8 planes x 484 px, stride 7744 B): conflict-free
//   b128 reads AND writes (uniform 8 lanes / 4-bank group).
// K-loop: ROLLED over kh (7 iters), kw-row fully unrolled -> body ~3.3 KB
//   (I-cache hot; R4's 30 KB straight-line body was fetch-bound: MfmaUtil 20%,
//   VALUBusy 6%, everything idle). A-reads are immediate-offset ds_read_b128
//   off ONE rolling per-lane base (+176 shorts/row); B-loads roll one
//   per-lane pointer (+3584 frag8/row). ~35 VALU per 224-MFMA row.
// B taps: direct-from-global (L2-resident), no LDS, no barriers in K-loop.
// Epilogue: fused BN partial sums via q-lane shfl + atomicAdd.
// ---------------------------------------------------------------------------
__global__ __launch_bounds__(256) void conv_z_mfma(
        const short* __restrict__ srcT,  // [31,HW,64] bf16 (tmp_t)
        const short* __restrict__ wfrag, // per-layer B-frag buffer (bf16 bits)
        const float* __restrict__ bias,  // [64]
        float* __restrict__ dst,         // [31,64,HW] (zpre)
        float* __restrict__ pstats)      // [31*64][2] partial sums (pre-zeroed)
{
    __shared__ __align__(16) short a_s[8 * PLSTRIDE]; // 61,952 B

    int s    = blockIdx.y;
    int tile = blockIdx.x;
    int h0 = (tile >> 3) << 4, w0 = (tile & 7) << 4;
    int tid  = threadIdx.x;
    int wave = tid >> 6, lane = tid & 63;
    int q = lane >> 4, m = lane & 15;

    // ---- stage A: bf16 [pix][ic] -> plane-major LDS; all b128, conflict-free
    const short* tsrc = srcT + (size_t)s * HW * KC;
#pragma unroll
    for (int rep = 0; rep < 2; rep++) {
        int p = tid + rep * 256;
        if (p < 484) {
            int r = p / 22, c = p - r * 22;
            int hh = h0 - 3 + r, ww = w0 - 3 + c;
            bool ok = (hh >= 0 && hh < IMG && ww >= 0 && ww < IMG);
            const short* px = tsrc + ((size_t)(ok ? (hh * IMG + ww) : 0) << 6);
            short* dp = a_s + p * 8;
#pragma unroll
            for (int c8 = 0; c8 < 8; c8++) {
                frag8 v;
                if (ok) v = *(const frag8*)(px + (c8 << 3));
                else    v = (frag8)(short)0;
                *(frag8*)(dp + c8 * PLSTRIDE) = v;
            }
        }
    }

    facc4 acc[4][4];
#pragma unroll
    for (int i = 0; i < 4; i++)
#pragma unroll
        for (int j = 0; j < 4; j++)
            acc[i][j] = (facc4){0.f, 0.f, 0.f, 0.f};

    __syncthreads();   // a_s ready; read-only from here: no more barriers

    // rolling per-lane bases: A row (kh) base and B row-of-taps base
    const short* arow = a_s + q * PLSTRIDE + (wave * 4 * 22 + m) * 8;
    const frag8* brow = (const frag8*)wfrag + lane;

#pragma unroll 1
    for (int kh = 0; kh < 7; ++kh) {
#pragma unroll
        for (int kw = 0; kw < 7; ++kw) {
            frag8 b[8];
#pragma unroll
            for (int f = 0; f < 8; ++f) b[f] = brow[kw * 512 + f * 64];
#pragma unroll
            for (int ks = 0; ks < 2; ++ks) {
                // immediate offsets: ks*30976 + pg*176 + kw*8 shorts (<32 KB)
                frag8 a0 = *(const frag8*)(arow + ks * (4 * PLSTRIDE) + (0 * 22 + kw) * 8);
                frag8 a1 = *(const frag8*)(arow + ks * (4 * PLSTRIDE) + (1 * 22 + kw) * 8);
                frag8 a2 = *(const frag8*)(arow + ks * (4 * PLSTRIDE) + (2 * 22 + kw) * 8);
                frag8 a3 = *(const frag8*)(arow + ks * (4 * PLSTRIDE) + (3 * 22 + kw) * 8);
                acc[0][0] = __builtin_amdgcn_mfma_f32_16x16x32_bf16(a0, b[ks*4+0], acc[0][0], 0, 0, 0);
                acc[0][1] = __builtin_amdgcn_mfma_f32_16x16x32_bf16(a0, b[ks*4+1], acc[0][1], 0, 0, 0);
                acc[0][2] = __builtin_amdgcn_mfma_f32_16x16x32_bf16(a0, b[ks*4+2], acc[0][2], 0, 0, 0);
                acc[0][3] = __builtin_amdgcn_mfma_f32_16x16x32_bf16(a0, b[ks*4+3], acc[0][3], 0, 0, 0);
                acc[1][0] = __builtin_amdgcn_mfma_f32_16x16x32_bf16(a1, b[ks*4+0], acc[1][0], 0, 0, 0);
                acc[1][1] = __builtin_amdgcn_mfma_f32_16x16x32_bf16(a1, b[ks*4+1], acc[1][1], 0, 0, 0);
                acc[1][2] = __builtin_amdgcn_mfma_f32_16x16x32_bf16(a1, b[ks*4+2], acc[1][2], 0, 0, 0);
                acc[1][3] = __builtin_amdgcn_mfma_f32_16x16x32_bf16(a1, b[ks*4+3], acc[1][3], 0, 0, 0);
                acc[2][0] = __builtin_amdgcn_mfma_f32_16x16x32_bf16(a2, b[ks*4+0], acc[2][0], 0, 0, 0);
                acc[2][1] = __builtin_amdgcn_mfma_f32_16x16x32_bf16(a2, b[ks*4+1], acc[2][1], 0, 0, 0);
                acc[2][2] = __builtin_amdgcn_mfma_f32_16x16x32_bf16(a2, b[ks*4+2], acc[2][2], 0, 0, 0);
                acc[2][3] = __builtin_amdgcn_mfma_f32_16x16x32_bf16(a2, b[ks*4+3], acc[2][3], 0, 0, 0);
                acc[3][0] = __builtin_amdgcn_mfma_f32_16x16x32_bf16(a3, b[ks*4+0], acc[3][0], 0, 0, 0);
                acc[3][1] = __builtin_amdgcn_mfma_f32_16x16x32_bf16(a3, b[ks*4+1], acc[3][1], 0, 0, 0);
                acc[3][2] = __builtin_amdgcn_mfma_f32_16x16x32_bf16(a3, b[ks*4+2], acc[3][2], 0, 0, 0);
                acc[3][3] = __builtin_amdgcn_mfma_f32_16x16x32_bf16(a3, b[ks*4+3], acc[3][3], 0, 0, 0);
            }
        }
        arow += 22 * 8;     // next kh row of the A tile
        brow += 7 * 512;    // next row of 7 taps in wz_frag
    }

    // ---- epilogue: D layout col(oc-part)=lane&15, row(px col)=q*4+reg
    //      + fused BN partial sums (per oc: reduce over q-lanes, atomicAdd)
    int prow = h0 + wave * 4;
#pragma unroll
    for (int og = 0; og < 4; og++) {
        int oc = og * 16 + m;
        float bb = bias[oc];
        float s1 = 0.f, s2 = 0.f;
#pragma unroll
        for (int pg = 0; pg < 4; pg++) {
            float* dp = dst + ((size_t)s * KC + oc) * HW
                            + (size_t)(prow + pg) * IMG + w0 + q * 4;
            float4 v;
            v.x = acc[pg][og][0] + bb;
            v.y = acc[pg][og][1] + bb;
            v.z = acc[pg][og][2] + bb;
            v.w = acc[pg][og][3] + bb;
            s1 += v.x + v.y + v.z + v.w;
            s2 += v.x * v.x + v.y * v.y + v.z * v.z + v.w * v.w;
            *(float4*)dp = v;
        }
        // reduce over the 4 q-lanes sharing this oc (lane bits 4,5)
        s1 += __shfl_xor(s1, 16, 64); s2 += __shfl_xor(s2, 16, 64);
        s1 += __shfl_xor(s1, 32, 64); s2 += __shfl_xor(s2, 32, 64);
        if (q == 0) {
            atomicAdd(&pstats[(s * KC + oc) * 2],     s1);
            atomicAdd(&pstats[(s * KC + oc) * 2 + 1], s2);
        }
    }
}

// ---------------------------------------------------------------------------
// Finalize BN stats from fused partial sums; re-zero pstats for next iter.
// ---------------------------------------------------------------------------
__global__ __launch_bounds__(64) void bn_finalize(
        float* __restrict__ pstats,   // [31*64][2] partial sums
        float* __restrict__ stats)    // [31*64][2] -> (mu, rsqrt(var+eps))
{
    int i = blockIdx.x * 64 + threadIdx.x;
    if (i < S31 * KC) {
        float s1 = pstats[i * 2], s2 = pstats[i * 2 + 1];
        pstats[i * 2] = 0.f;
        pstats[i * 2 + 1] = 0.f;
        float mu  = s1 * (1.f / HW);
        float var = s2 * (1.f / HW) - mu * mu;
        if (var < 0.f) var = 0.f;
        stats[i * 2]     = mu;
        stats[i * 2 + 1] = rsqrtf(var + BNEPS);
    }
}

// ---------------------------------------------------------------------------
// Directional gated band scan: each thread owns one (c,h,w), walks 31 bands.
// ---------------------------------------------------------------------------
__global__ __launch_bounds__(256) void band_scan(
        const float* __restrict__ tmp,   // [31,64,HW]
        const float* __restrict__ zpre,  // [31,64,HW]
        const float* __restrict__ stats, // [31*64][2]
        const float* __restrict__ gamma, // [64]
        const float* __restrict__ beta,  // [64]
        float* __restrict__ csc,         // [31,64,HW]
        int fwd)
{
    int idx = blockIdx.x * 256 + threadIdx.x;  // 0 .. 64*HW-1
    int c = idx >> 14;
    float g = gamma[c], be = beta[c];
    float prev = 0.f;
    for (int step = 0; step < S31; step++) {
        int s = fwd ? step : (S31 - 1 - step);
        size_t off = (size_t)s * KC * HW + idx;
        float t  = tmp[off];
        float zp = zpre[off];
        float mu = stats[(s * KC + c) * 2];
        float rs = stats[(s * KC + c) * 2 + 1];
        float zn = (zp - mu) * rs * g + be;
        float z  = 1.f / (1.f + expf(-zn));
        float cur = (step == 0) ? t : (z * prev + (1.f - z) * t);
        csc[off] = cur;
        prev = cur;
    }
}

// ---------------------------------------------------------------------------
extern "C" void kernel_launch(void* const* d_in, const int* in_sizes, int n_in,
                              void* d_out, int out_size, void* d_ws, size_t ws_size,
                              hipStream_t stream) {
    const float* x      = (const float*)d_in[0];   // [1,31,128,128]
    const float* W_fe   = (const float*)d_in[1];
    const float* b_fe   = (const float*)d_in[2];
    const float* W_enc  = (const float*)d_in[3];
    const float* b_enc  = (const float*)d_in[4];
    const float* W_dec  = (const float*)d_in[5];
    const float* b_dec  = (const float*)d_in[6];
    const float* W_last = (const float*)d_in[7];
    const float* b_last = (const float*)d_in[8];
    const float* W_z    = (const float*)d_in[9];
    const float* b_z    = (const float*)d_in[10];
    const float* bn_g   = (const float*)d_in[11];
    const float* bn_b   = (const float*)d_in[12];

    float* out     = (float*)d_out;
    float* csc     = out;                               // [31,1,64,128,128]
    float* outputs = out + (size_t)S31 * KC * HW;       // [1,31,128,128]

    char* ws = (char*)d_ws;
    float* tmp     = (float*)ws; ws += (size_t)S31 * KC * HW * 4;
    float* zpre    = (float*)ws; ws += (size_t)S31 * KC * HW * 4;
    float* res     = (float*)ws; ws += (size_t)S31 * HW * 4;
    float* stats   = (float*)ws; ws += (size_t)S31 * KC * 2 * 4;
    float* pstats  = (float*)ws; ws += (size_t)S31 * KC * 2 * 4;
    short* wz_frag = (short*)ws; ws += (size_t)3 * KK * 4096 * 2;  // bf16 frags
    float* wenc_r  = (float*)ws; ws += (size_t)3 * KK * KC * 4;
    float* wfe_r   = (float*)ws; ws += (size_t)KK * KC * 4;
    short* tmp_t   = (short*)ws; ws += (size_t)S31 * HW * KC * 2;  // bf16 pix-major

    // 1) weight reorder / frag-swizzle (+ zero pstats)
    {
        int total = 3 * KK * 4096 + 3 * KK * KC + KK * KC + 2 * S31 * KC;
        reorder_weights<<<(total + 255) / 256, 256, 0, stream>>>(
            W_z, W_enc, W_fe, wz_frag, wenc_r, wfe_r, pstats);
    }

    dim3 gconv(64, S31);

    // 2) csc = softshrink(conv_fe(x))
    conv1to64<<<gconv, 512, 0, stream>>>(x, wfe_r, b_fe, nullptr, csc, nullptr);

    for (int it = 0; it < 3; it++) {
        int lyr = it;
        // res = x - (conv_dec(csc) + b_dec)
        conv64to1<<<gconv, 256, 0, stream>>>(
            csc, W_dec + (size_t)lyr * KC * KK, b_dec + lyr, x, res);
        // tmp = softshrink(csc + conv_enc(res) + b_enc)  (+ bf16 pix-major copy)
        conv1to64<<<gconv, 512, 0, stream>>>(
            res, wenc_r + (size_t)lyr * KK * KC, b_enc + (size_t)lyr * KC, csc,
            tmp, tmp_t);
        // zpre = conv_z(tmp) + b_z   (bf16 MFMA shift-GEMM, plane-major LDS,
        //                             kh-rolled / kw-unrolled hot loop, fused BN)
        conv_z_mfma<<<gconv, 256, 0, stream>>>(
            tmp_t, wz_frag + (size_t)lyr * KK * 4096, b_z + (size_t)lyr * KC,
            zpre, pstats);
        // BN finalize (also re-zeroes pstats for the next iteration)
        bn_finalize<<<S31, 64, 0, stream>>>(pstats, stats);
        // gated directional scan -> csc
        band_scan<<<(KC * HW) / 256, 256, 0, stream>>>(
            tmp, zpre, stats, bn_g + (size_t)lyr * KC, bn_b + (size_t)lyr * KC,
            csc, (it % 2 == 0) ? 1 : 0);
    }

    // 3) outputs = conv_last(csc) + b_last
    conv64to1<<<gconv, 256, 0, stream>>>(csc, W_last, b_last, nullptr, outputs);
}

// Round 6
// 2276.631 us; speedup vs baseline: 1.2531x; 1.1038x over previous
//
#include <hip/hip_runtime.h>
#include <hip/hip_bf16.h>
#include <math.h>

// Problem constants
#define S31   31
#define KC    64
#define KS    7
#define KK    49          // 7*7
#define IMG   128
#define HW    16384       // 128*128
#define LAM   0.1f
#define BNEPS 1e-5f

// conv_z A-tile: plane-major LDS. 4 planes (16B ic-chunks) x 484 pixels,
// HALF the ic range at a time (ks-split, two passes). 30,976 B.
#define PLSTRIDE 3872     // shorts per plane (484 * 8)

// 32x8 tiles for the direct convs (full 128-B cacheline rows)
#define TW    32
#define TH    8
#define DTW   38          // TW + 6
#define DTH   14          // TH + 6
#define DTILE 532         // DTW * DTH

typedef __attribute__((ext_vector_type(8))) short  frag8;   // 8 bf16 (4 VGPRs)
typedef __attribute__((ext_vector_type(4))) float  facc4;   // 4 fp32 acc

// fp32 -> bf16 bits, RNE
static __device__ __forceinline__ short f2bf(float f) {
    union { float f; unsigned u; } x; x.f = f;
    unsigned r = x.u + 0x7fffu + ((x.u >> 16) & 1u);
    return (short)(r >> 16);
}

// ---------------------------------------------------------------------------
// Weight reorder:
//  wz_frag[lyr][khkw][frag f=ks*4+og][lane][j] (bf16) — exact MFMA B-fragment
//    order for 16x16x32: k(=ic) = ks*32 + (lane>>4)*8 + j, n(=oc) = og*16 + (lane&15)
//  wenc_r[lyr][k][oc], wfe_r[k][oc] (fp32)
//  tail: zero pstats (BN partial-sum accumulator)
// ---------------------------------------------------------------------------
__global__ void reorder_weights(const float* __restrict__ Wz,
                                const float* __restrict__ Wenc,
                                const float* __restrict__ Wfe,
                                short* __restrict__ wz_frag,
                                float* __restrict__ wenc_r,
                                float* __restrict__ wfe_r,
                                float* __restrict__ pstats) {
    int tid = blockIdx.x * 256 + threadIdx.x;
    const int NZ = 3 * KK * 4096;         // 602112 frag elements
    const int NE = 3 * KK * KC;           // 9408
    const int NF = KK * KC;               // 3136
    const int NP = 2 * S31 * KC;          // 3968 pstats floats
    if (tid < NZ) {
        int j    = tid & 7;
        int lane = (tid >> 3) & 63;
        int og   = (tid >> 9) & 3;
        int ks   = (tid >> 11) & 1;
        int rem  = tid >> 12;            // lyr*49 + khkw
        int khkw = rem % KK;
        int lyr  = rem / KK;
        int ic = ks * 32 + ((lane >> 4) << 3) + j;
        int oc = (og << 4) + (lane & 15);
        float w = Wz[(((size_t)lyr * KC + oc) * KC + ic) * KK + khkw];
        wz_frag[tid] = f2bf(w);
    } else if (tid < NZ + NE) {
        int t = tid - NZ;
        int oc = t & 63;
        int kk = t >> 6;
        int k  = kk % KK;
        int lyr = kk / KK;
        wenc_r[t] = Wenc[((size_t)lyr * KC + oc) * KK + k];
    } else if (tid < NZ + NE + NF) {
        int t = tid - NZ - NE;
        int oc = t & 63;
        int k  = t >> 6;
        wfe_r[t] = Wfe[oc * KK + k];
    } else if (tid < NZ + NE + NF + NP) {
        pstats[tid - NZ - NE - NF] = 0.f;
    }
}

// ---------------------------------------------------------------------------
// 1 -> 64 channel conv (+optional add) + softshrink.
// 512 threads: 32x8 pixel tile (full-cacheline rows), oc split in two halves
// of 32. addsrc is prefetched into a 32-deep register array BEFORE the
// compute loop. Optionally also emits a bf16 PIXEL-MAJOR copy dst_t[s][pix][ic].
// ---------------------------------------------------------------------------
__global__ __launch_bounds__(512) void conv1to64(
        const float* __restrict__ src,    // [31, HW]
        const float* __restrict__ wr,     // [49*64] layout [k][oc]
        const float* __restrict__ bias,   // [64]
        const float* __restrict__ addsrc, // [31,64,HW] or nullptr
        float* __restrict__ dst,          // [31,64,HW]
        short* __restrict__ dst_t)        // [31,HW,64] bf16 or nullptr
{
    int s    = blockIdx.y;
    int tile = blockIdx.x;                // 4 tiles in w (32 wide), 16 in h (8 tall)
    int half = threadIdx.x >> 8;          // 0/1 -> oc 0..31 / 32..63
    int t    = threadIdx.x & 255;
    int tx = t & 31, ty = t >> 5;
    int w0 = (tile & 3) << 5, h0 = (tile >> 2) << 3;

    __shared__ float t_s[DTILE];
    const float* sp = src + (size_t)s * HW;
    for (int i = threadIdx.x; i < DTILE; i += 512) {
        int r = i / DTW, c = i - r * DTW;
        int hh = h0 - 3 + r, ww = w0 - 3 + c;
        t_s[i] = (hh >= 0 && hh < IMG && ww >= 0 && ww < IMG) ? sp[hh * IMG + ww] : 0.f;
    }
    __syncthreads();

    int pix = (h0 + ty) * IMG + (w0 + tx);
    size_t base = ((size_t)s * KC + half * 32) * HW + pix;

    // 32-deep prefetch of addsrc (issued before the compute loop, kept live)
    float addv[32];
    if (addsrc) {
#pragma unroll
        for (int i = 0; i < 32; i++) addv[i] = addsrc[base + (size_t)i * HW];
    } else {
#pragma unroll
        for (int i = 0; i < 32; i++) addv[i] = 0.f;
    }
    __builtin_amdgcn_sched_barrier(0);   // keep the loads issued up here

    float acc[32];
#pragma unroll
    for (int i = 0; i < 32; i++) acc[i] = 0.f;

    const float* wrh = wr + half * 32;
#pragma unroll 1
    for (int kh = 0; kh < KS; kh++) {
#pragma unroll
        for (int kw = 0; kw < KS; kw++) {
            float v = t_s[(ty + kh) * DTW + tx + kw];
            const float* wk = wrh + (kh * KS + kw) * KC;
#pragma unroll
            for (int i = 0; i < 32; i++) acc[i] += v * wk[i];
        }
    }

#pragma unroll
    for (int g = 0; g < 4; g++) {
        frag8 vv;
#pragma unroll
        for (int j = 0; j < 8; j++) {
            int i = g * 8 + j;
            float v = acc[i] + bias[half * 32 + i];   // same assoc order as R2
            v += addv[i];                             // (+0.0f when no addsrc)
            v = (v > LAM) ? (v - LAM) : ((v < -LAM) ? (v + LAM) : 0.f);
            dst[base + (size_t)i * HW] = v;
            vv[j] = f2bf(v);
        }
        if (dst_t) {
            *(frag8*)(dst_t + ((size_t)s * HW + pix) * KC + half * 32 + g * 8) = vv;
        }
    }
}

// ---------------------------------------------------------------------------
// 64 -> 1 channel conv. If xsub != null, out = xsub - (conv+b); else conv+b.
// 32x8 tile; ic staged 4 planes/round, double-buffered LDS with register
// prefetch. Accumulation order (ic asc, kh, kw) identical -> bit-exact.
// ---------------------------------------------------------------------------
#define ICB   4
#define CHUNK (ICB * DTILE)   // 2128

__global__ __launch_bounds__(256) void conv64to1(
        const float* __restrict__ src,   // [31,64,HW]
        const float* __restrict__ w,     // [64*49] layout [ic][k]
        const float* __restrict__ bias,  // [1]
        const float* __restrict__ xsub,  // [31,HW] or nullptr
        float* __restrict__ dst)         // [31,HW]
{
    int s    = blockIdx.y;
    int tile = blockIdx.x;
    int tx = threadIdx.x & 31, ty = threadIdx.x >> 5;
    int w0 = (tile & 3) << 5, h0 = (tile >> 2) << 3;

    __shared__ float t_s[2][CHUNK];      // 17 KB

    // per-thread load slots: identical pattern every chunk, precompute once
    int  goff[9];
    bool okf[9];
#pragma unroll
    for (int r = 0; r < 9; r++) {
        int j = threadIdx.x + r * 256;
        if (j < CHUNK) {
            int plane = j / DTILE, p = j - plane * DTILE;
            int rr = p / DTW, cc = p - rr * DTW;
            int hh = h0 - 3 + rr, ww = w0 - 3 + cc;
            bool inb = (hh >= 0 && hh < IMG && ww >= 0 && ww < IMG);
            goff[r] = plane * HW + (inb ? (hh * IMG + ww) : 0);
            okf[r]  = inb;
        }
    }

    const float* sbase = src + (size_t)s * KC * HW;

    // stage chunk 0
    float ldv[9];
#pragma unroll
    for (int r = 0; r < 9; r++)
        if (threadIdx.x + r * 256 < CHUNK)
            ldv[r] = okf[r] ? sbase[goff[r]] : 0.f;
#pragma unroll
    for (int r = 0; r < 9; r++)
        if (threadIdx.x + r * 256 < CHUNK)
            t_s[0][threadIdx.x + r * 256] = ldv[r];

    float acc = 0.f;
    __syncthreads();

#pragma unroll 1
    for (int blk = 0; blk < 16; blk++) {
        int cur = blk & 1;
        // prefetch next chunk into regs (overlaps the compute below)
        if (blk < 15) {
            const float* nb = sbase + (size_t)(blk + 1) * ICB * HW;
#pragma unroll
            for (int r = 0; r < 9; r++)
                if (threadIdx.x + r * 256 < CHUNK)
                    ldv[r] = okf[r] ? nb[goff[r]] : 0.f;
        }
        __builtin_amdgcn_sched_barrier(0);
        // compute 4 planes of this chunk
#pragma unroll
        for (int pl = 0; pl < ICB; pl++) {
            int ic = blk * ICB + pl;
            const float* wk = w + ic * KK;
            const float* ts = &t_s[cur][pl * DTILE];
#pragma unroll 1
            for (int kh = 0; kh < KS; kh++) {
#pragma unroll
                for (int kw = 0; kw < KS; kw++)
                    acc += ts[(ty + kh) * DTW + tx + kw] * wk[kh * KS + kw];
            }
        }
        __syncthreads();
        if (blk < 15) {
#pragma unroll
            for (int r = 0; r < 9; r++)
                if (threadIdx.x + r * 256 < CHUNK)
                    t_s[cur ^ 1][threadIdx.x + r * 256] = ldv[r];
            __syncthreads();
        }
    }

    float v = acc + bias[0];
    int pix = (h0 + ty) * IMG + (w0 + tx);
    if (xsub) v = xsub[(size_t)s * HW + pix] - v;
    dst[(size_t)s * HW + pix] = v;
}

// ---------------------------------------------------------------------------
// conv_z as bf16 MFMA shift-GEMM: zpre[s][oc][px] = sum_{ic,kh,kw} ...
// Block: 256 thr (4 waves) = 16x16 pixel tile x 64 oc, all 49 taps.
// OCCUPANCY FIX (R6): R5 was pinned at 2 waves/SIMD by BOTH 62 KB LDS (2
//   blocks/CU) and 152 unified regs (88 VGPR + 64 AGPR). Now:
//   - ks-SPLIT: two passes over the taps; pass p stages only ic [p*32,p*32+32)
//     -> LDS 30,976 B -> 4 blocks/CU. acc persists in regs across passes.
//   - __launch_bounds__(256, 4): caps regs at 128/wave -> 4 waves/SIMD.
//   16 waves/CU total: 3 partner waves to hide B-load (L2 ~200-300 cyc) and
//   ds_read latency instead of 1.
// A tile: plane-major (4 planes x 484 px, stride 7744 B), conflict-light b128.
// K-loop: kh rolled (7 iters), kw unrolled -> ~1.7 KB body, I-cache hot.
// B taps: direct-from-global (L2-resident), no LDS, no barriers in tap loop.
// NOTE: accumulation order is now (all taps @ ks=0) then (all taps @ ks=1) —
//   mathematically identical, ULP-level fp difference vs per-tap interleave.
// Epilogue: fused BN partial sums via q-lane shfl + atomicAdd.
// ---------------------------------------------------------------------------
__global__ __launch_bounds__(256, 4) void conv_z_mfma(
        const short* __restrict__ srcT,  // [31,HW,64] bf16 (tmp_t)
        const short* __restrict__ wfrag, // per-layer B-frag buffer (bf16 bits)
        const float* __restrict__ bias,  // [64]
        float* __restrict__ dst,         // [31,64,HW] (zpre)
        float* __restrict__ pstats)      // [31*64][2] partial sums (pre-zeroed)
{
    __shared__ __align__(16) short a_s[4 * PLSTRIDE]; // 30,976 B

    int s    = blockIdx.y;
    int tile = blockIdx.x;
    int h0 = (tile >> 3) << 4, w0 = (tile & 7) << 4;
    int tid  = threadIdx.x;
    int wave = tid >> 6, lane = tid & 63;
    int q = lane >> 4, m = lane & 15;

    const short* tsrc = srcT + (size_t)s * HW * KC;

    facc4 acc[4][4];
#pragma unroll
    for (int i = 0; i < 4; i++)
#pragma unroll
        for (int j = 0; j < 4; j++)
            acc[i][j] = (facc4){0.f, 0.f, 0.f, 0.f};

#pragma unroll 1
    for (int pass = 0; pass < 2; ++pass) {
        if (pass) __syncthreads();       // all pass-0 reads done before overwrite

        // ---- stage ic half [pass*32, pass*32+32) -> planes 0..3 (b128 only)
#pragma unroll
        for (int rep = 0; rep < 2; rep++) {
            int p = tid + rep * 256;
            if (p < 484) {
                int r = p / 22, c = p - r * 22;
                int hh = h0 - 3 + r, ww = w0 - 3 + c;
                bool ok = (hh >= 0 && hh < IMG && ww >= 0 && ww < IMG);
                const short* px = tsrc + ((size_t)(ok ? (hh * IMG + ww) : 0) << 6)
                                       + (pass << 5);
                short* dp = a_s + p * 8;
#pragma unroll
                for (int c4 = 0; c4 < 4; c4++) {
                    frag8 v;
                    if (ok) v = *(const frag8*)(px + (c4 << 3));
                    else    v = (frag8)(short)0;
                    *(frag8*)(dp + c4 * PLSTRIDE) = v;
                }
            }
        }
        __syncthreads();

        // rolling per-lane bases: A row (kh) base and B row-of-taps base
        const short* arow = a_s + q * PLSTRIDE + (wave * 4 * 22 + m) * 8;
        const frag8* brow = (const frag8*)wfrag + (pass * 4) * 64 + lane;

#pragma unroll 1
        for (int kh = 0; kh < 7; ++kh) {
#pragma unroll
            for (int kw = 0; kw < 7; ++kw) {
                frag8 b0 = brow[kw * 512 + 0 * 64];
                frag8 b1 = brow[kw * 512 + 1 * 64];
                frag8 b2 = brow[kw * 512 + 2 * 64];
                frag8 b3 = brow[kw * 512 + 3 * 64];
                frag8 a0 = *(const frag8*)(arow + (0 * 22 + kw) * 8);
                frag8 a1 = *(const frag8*)(arow + (1 * 22 + kw) * 8);
                frag8 a2 = *(const frag8*)(arow + (2 * 22 + kw) * 8);
                frag8 a3 = *(const frag8*)(arow + (3 * 22 + kw) * 8);
                acc[0][0] = __builtin_amdgcn_mfma_f32_16x16x32_bf16(a0, b0, acc[0][0], 0, 0, 0);
                acc[0][1] = __builtin_amdgcn_mfma_f32_16x16x32_bf16(a0, b1, acc[0][1], 0, 0, 0);
                acc[0][2] = __builtin_amdgcn_mfma_f32_16x16x32_bf16(a0, b2, acc[0][2], 0, 0, 0);
                acc[0][3] = __builtin_amdgcn_mfma_f32_16x16x32_bf16(a0, b3, acc[0][3], 0, 0, 0);
                acc[1][0] = __builtin_amdgcn_mfma_f32_16x16x32_bf16(a1, b0, acc[1][0], 0, 0, 0);
                acc[1][1] = __builtin_amdgcn_mfma_f32_16x16x32_bf16(a1, b1, acc[1][1], 0, 0, 0);
                acc[1][2] = __builtin_amdgcn_mfma_f32_16x16x32_bf16(a1, b2, acc[1][2], 0, 0, 0);
                acc[1][3] = __builtin_amdgcn_mfma_f32_16x16x32_bf16(a1, b3, acc[1][3], 0, 0, 0);
                acc[2][0] = __builtin_amdgcn_mfma_f32_16x16x32_bf16(a2, b0, acc[2][0], 0, 0, 0);
                acc[2][1] = __builtin_amdgcn_mfma_f32_16x16x32_bf16(a2, b1, acc[2][1], 0, 0, 0);
                acc[2][2] = __builtin_amdgcn_mfma_f32_16x16x32_bf16(a2, b2, acc[2][2], 0, 0, 0);
                acc[2][3] = __builtin_amdgcn_mfma_f32_16x16x32_bf16(a2, b3, acc[2][3], 0, 0, 0);
                acc[3][0] = __builtin_amdgcn_mfma_f32_16x16x32_bf16(a3, b0, acc[3][0], 0, 0, 0);
                acc[3][1] = __builtin_amdgcn_mfma_f32_16x16x32_bf16(a3, b1, acc[3][1], 0, 0, 0);
                acc[3][2] = __builtin_amdgcn_mfma_f32_16x16x32_bf16(a3, b2, acc[3][2], 0, 0, 0);
                acc[3][3] = __builtin_amdgcn_mfma_f32_16x16x32_bf16(a3, b3, acc[3][3], 0, 0, 0);
            }
            arow += 22 * 8;     // next kh row of the A tile
            brow += 7 * 512;    // next row of 7 taps in wz_frag
        }
    }

    // ---- epilogue: D layout col(oc-part)=lane&15, row(px col)=q*4+reg
    //      + fused BN partial sums (per oc: reduce over q-lanes, atomicAdd)
    int prow = h0 + wave * 4;
#pragma unroll
    for (int og = 0; og < 4; og++) {
        int oc = og * 16 + m;
        float bb = bias[oc];
        float s1 = 0.f, s2 = 0.f;
#pragma unroll
        for (int pg = 0; pg < 4; pg++) {
            float* dp = dst + ((size_t)s * KC + oc) * HW
                            + (size_t)(prow + pg) * IMG + w0 + q * 4;
            float4 v;
            v.x = acc[pg][og][0] + bb;
            v.y = acc[pg][og][1] + bb;
            v.z = acc[pg][og][2] + bb;
            v.w = acc[pg][og][3] + bb;
            s1 += v.x + v.y + v.z + v.w;
            s2 += v.x * v.x + v.y * v.y + v.z * v.z + v.w * v.w;
            *(float4*)dp = v;
        }
        // reduce over the 4 q-lanes sharing this oc (lane bits 4,5)
        s1 += __shfl_xor(s1, 16, 64); s2 += __shfl_xor(s2, 16, 64);
        s1 += __shfl_xor(s1, 32, 64); s2 += __shfl_xor(s2, 32, 64);
        if (q == 0) {
            atomicAdd(&pstats[(s * KC + oc) * 2],     s1);
            atomicAdd(&pstats[(s * KC + oc) * 2 + 1], s2);
        }
    }
}

// ---------------------------------------------------------------------------
// Finalize BN stats from fused partial sums; re-zero pstats for next iter.
// ---------------------------------------------------------------------------
__global__ __launch_bounds__(64) void bn_finalize(
        float* __restrict__ pstats,   // [31*64][2] partial sums
        float* __restrict__ stats)    // [31*64][2] -> (mu, rsqrt(var+eps))
{
    int i = blockIdx.x * 64 + threadIdx.x;
    if (i < S31 * KC) {
        float s1 = pstats[i * 2], s2 = pstats[i * 2 + 1];
        pstats[i * 2] = 0.f;
        pstats[i * 2 + 1] = 0.f;
        float mu  = s1 * (1.f / HW);
        float var = s2 * (1.f / HW) - mu * mu;
        if (var < 0.f) var = 0.f;
        stats[i * 2]     = mu;
        stats[i * 2 + 1] = rsqrtf(var + BNEPS);
    }
}

// ---------------------------------------------------------------------------
// Directional gated band scan: each thread owns one (c,h,w), walks 31 bands.
// ---------------------------------------------------------------------------
__global__ __launch_bounds__(256) void band_scan(
        const float* __restrict__ tmp,   // [31,64,HW]
        const float* __restrict__ zpre,  // [31,64,HW]
        const float* __restrict__ stats, // [31*64][2]
        const float* __restrict__ gamma, // [64]
        const float* __restrict__ beta,  // [64]
        float* __restrict__ csc,         // [31,64,HW]
        int fwd)
{
    int idx = blockIdx.x * 256 + threadIdx.x;  // 0 .. 64*HW-1
    int c = idx >> 14;
    float g = gamma[c], be = beta[c];
    float prev = 0.f;
    for (int step = 0; step < S31; step++) {
        int s = fwd ? step : (S31 - 1 - step);
        size_t off = (size_t)s * KC * HW + idx;
        float t  = tmp[off];
        float zp = zpre[off];
        float mu = stats[(s * KC + c) * 2];
        float rs = stats[(s * KC + c) * 2 + 1];
        float zn = (zp - mu) * rs * g + be;
        float z  = 1.f / (1.f + expf(-zn));
        float cur = (step == 0) ? t : (z * prev + (1.f - z) * t);
        csc[off] = cur;
        prev = cur;
    }
}

// ---------------------------------------------------------------------------
extern "C" void kernel_launch(void* const* d_in, const int* in_sizes, int n_in,
                              void* d_out, int out_size, void* d_ws, size_t ws_size,
                              hipStream_t stream) {
    const float* x      = (const float*)d_in[0];   // [1,31,128,128]
    const float* W_fe   = (const float*)d_in[1];
    const float* b_fe   = (const float*)d_in[2];
    const float* W_enc  = (const float*)d_in[3];
    const float* b_enc  = (const float*)d_in[4];
    const float* W_dec  = (const float*)d_in[5];
    const float* b_dec  = (const float*)d_in[6];
    const float* W_last = (const float*)d_in[7];
    const float* b_last = (const float*)d_in[8];
    const float* W_z    = (const float*)d_in[9];
    const float* b_z    = (const float*)d_in[10];
    const float* bn_g   = (const float*)d_in[11];
    const float* bn_b   = (const float*)d_in[12];

    float* out     = (float*)d_out;
    float* csc     = out;                               // [31,1,64,128,128]
    float* outputs = out + (size_t)S31 * KC * HW;       // [1,31,128,128]

    char* ws = (char*)d_ws;
    float* tmp     = (float*)ws; ws += (size_t)S31 * KC * HW * 4;
    float* zpre    = (float*)ws; ws += (size_t)S31 * KC * HW * 4;
    float* res     = (float*)ws; ws += (size_t)S31 * HW * 4;
    float* stats   = (float*)ws; ws += (size_t)S31 * KC * 2 * 4;
    float* pstats  = (float*)ws; ws += (size_t)S31 * KC * 2 * 4;
    short* wz_frag = (short*)ws; ws += (size_t)3 * KK * 4096 * 2;  // bf16 frags
    float* wenc_r  = (float*)ws; ws += (size_t)3 * KK * KC * 4;
    float* wfe_r   = (float*)ws; ws += (size_t)KK * KC * 4;
    short* tmp_t   = (short*)ws; ws += (size_t)S31 * HW * KC * 2;  // bf16 pix-major

    // 1) weight reorder / frag-swizzle (+ zero pstats)
    {
        int total = 3 * KK * 4096 + 3 * KK * KC + KK * KC + 2 * S31 * KC;
        reorder_weights<<<(total + 255) / 256, 256, 0, stream>>>(
            W_z, W_enc, W_fe, wz_frag, wenc_r, wfe_r, pstats);
    }

    dim3 gconv(64, S31);

    // 2) csc = softshrink(conv_fe(x))
    conv1to64<<<gconv, 512, 0, stream>>>(x, wfe_r, b_fe, nullptr, csc, nullptr);

    for (int it = 0; it < 3; it++) {
        int lyr = it;
        // res = x - (conv_dec(csc) + b_dec)
        conv64to1<<<gconv, 256, 0, stream>>>(
            csc, W_dec + (size_t)lyr * KC * KK, b_dec + lyr, x, res);
        // tmp = softshrink(csc + conv_enc(res) + b_enc)  (+ bf16 pix-major copy)
        conv1to64<<<gconv, 512, 0, stream>>>(
            res, wenc_r + (size_t)lyr * KK * KC, b_enc + (size_t)lyr * KC, csc,
            tmp, tmp_t);
        // zpre = conv_z(tmp) + b_z   (bf16 MFMA shift-GEMM, ks-split LDS,
        //                             4 blocks/CU + 4 waves/SIMD, fused BN)
        conv_z_mfma<<<gconv, 256, 0, stream>>>(
            tmp_t, wz_frag + (size_t)lyr * KK * 4096, b_z + (size_t)lyr * KC,
            zpre, pstats);
        // BN finalize (also re-zeroes pstats for the next iteration)
        bn_finalize<<<S31, 64, 0, stream>>>(pstats, stats);
        // gated directional scan -> csc
        band_scan<<<(KC * HW) / 256, 256, 0, stream>>>(
            tmp, zpre, stats, bn_g + (size_t)lyr * KC, bn_b + (size_t)lyr * KC,
            csc, (it % 2 == 0) ? 1 : 0);
    }

    // 3) outputs = conv_last(csc) + b_last
    conv64to1<<<gconv, 256, 0, stream>>>(csc, W_last, b_last, nullptr, outputs);
}

// Round 7
// 1810.995 us; speedup vs baseline: 1.5753x; 1.2571x over previous
//
#include <hip/hip_runtime.h>
#include <hip/hip_bf16.h>
#include <math.h>

// Problem constants
#define S31   31
#define KC    64
#define KS    7
#define KK    49          // 7*7
#define IMG   128
#define HW    16384       // 128*128
#define LAM   0.1f
#define BNEPS 1e-5f

// conv_z A-tile: plane-major LDS. 4 planes (16B ic-chunks) x 484 pixels,
// HALF the ic range at a time (ks-split, two passes). 30,976 B.
#define PLSTRIDE 3872     // shorts per plane (484 * 8)

// 32x8 tiles for the direct convs (full 128-B cacheline rows)
#define TW    32
#define TH    8
#define DTW   38          // TW + 6
#define DTH   14          // TH + 6
#define DTILE 532         // DTW * DTH

typedef __attribute__((ext_vector_type(8))) short  frag8;   // 8 bf16 (4 VGPRs)
typedef __attribute__((ext_vector_type(4))) float  facc4;   // 4 fp32 acc

// fp32 -> bf16 bits, RNE
static __device__ __forceinline__ short f2bf(float f) {
    union { float f; unsigned u; } x; x.f = f;
    unsigned r = x.u + 0x7fffu + ((x.u >> 16) & 1u);
    return (short)(r >> 16);
}

// ---------------------------------------------------------------------------
// Weight reorder:
//  wz_frag[lyr][khkw][frag f=ks*4+og][lane][j] (bf16) — exact MFMA B-fragment
//    order for 16x16x32: k(=ic) = ks*32 + (lane>>4)*8 + j, n(=oc) = og*16 + (lane&15)
//  wenc_r[lyr][k][oc], wfe_r[k][oc] (fp32)
//  tail: zero pstats (BN partial-sum accumulator)
// ---------------------------------------------------------------------------
__global__ void reorder_weights(const float* __restrict__ Wz,
                                const float* __restrict__ Wenc,
                                const float* __restrict__ Wfe,
                                short* __restrict__ wz_frag,
                                float* __restrict__ wenc_r,
                                float* __restrict__ wfe_r,
                                float* __restrict__ pstats) {
    int tid = blockIdx.x * 256 + threadIdx.x;
    const int NZ = 3 * KK * 4096;         // 602112 frag elements
    const int NE = 3 * KK * KC;           // 9408
    const int NF = KK * KC;               // 3136
    const int NP = 2 * S31 * KC;          // 3968 pstats floats
    if (tid < NZ) {
        int j    = tid & 7;
        int lane = (tid >> 3) & 63;
        int og   = (tid >> 9) & 3;
        int ks   = (tid >> 11) & 1;
        int rem  = tid >> 12;            // lyr*49 + khkw
        int khkw = rem % KK;
        int lyr  = rem / KK;
        int ic = ks * 32 + ((lane >> 4) << 3) + j;
        int oc = (og << 4) + (lane & 15);
        float w = Wz[(((size_t)lyr * KC + oc) * KC + ic) * KK + khkw];
        wz_frag[tid] = f2bf(w);
    } else if (tid < NZ + NE) {
        int t = tid - NZ;
        int oc = t & 63;
        int kk = t >> 6;
        int k  = kk % KK;
        int lyr = kk / KK;
        wenc_r[t] = Wenc[((size_t)lyr * KC + oc) * KK + k];
    } else if (tid < NZ + NE + NF) {
        int t = tid - NZ - NE;
        int oc = t & 63;
        int k  = t >> 6;
        wfe_r[t] = Wfe[oc * KK + k];
    } else if (tid < NZ + NE + NF + NP) {
        pstats[tid - NZ - NE - NF] = 0.f;
    }
}

// ---------------------------------------------------------------------------
// 1 -> 64 channel conv (+optional add) + softshrink.
// R7: 256 threads/block, oc-half moved from threadIdx to BLOCKIDX (grid.x =
// 128 = 64 tiles x 2 halves). All weight/bias addresses are now workgroup-
// UNIFORM -> compiler emits s_load (scalar cache) instead of 1568 vector
// global loads per thread (R6: ~400 KB L1 traffic per wave for a 12.5 KB
// table = the hidden ~160 us). Per-thread work & accumulation order are
// IDENTICAL to R6 -> bit-exact.
// ---------------------------------------------------------------------------
__global__ __launch_bounds__(256) void conv1to64(
        const float* __restrict__ src,    // [31, HW]
        const float* __restrict__ wr,     // [49*64] layout [k][oc]
        const float* __restrict__ bias,   // [64]
        const float* __restrict__ addsrc, // [31,64,HW] or nullptr
        float* __restrict__ dst,          // [31,64,HW]
        short* __restrict__ dst_t)        // [31,HW,64] bf16 or nullptr
{
    int s    = blockIdx.y;
    int half = blockIdx.x & 1;            // 0/1 -> oc 0..31 / 32..63 (UNIFORM)
    int tile = blockIdx.x >> 1;           // 4 tiles in w (32 wide), 16 in h (8 tall)
    int t    = threadIdx.x;
    int tx = t & 31, ty = t >> 5;
    int w0 = (tile & 3) << 5, h0 = (tile >> 2) << 3;

    __shared__ float t_s[DTILE];
    const float* sp = src + (size_t)s * HW;
    for (int i = threadIdx.x; i < DTILE; i += 256) {
        int r = i / DTW, c = i - r * DTW;
        int hh = h0 - 3 + r, ww = w0 - 3 + c;
        t_s[i] = (hh >= 0 && hh < IMG && ww >= 0 && ww < IMG) ? sp[hh * IMG + ww] : 0.f;
    }
    __syncthreads();

    int pix = (h0 + ty) * IMG + (w0 + tx);
    size_t base = ((size_t)s * KC + half * 32) * HW + pix;

    // 32-deep prefetch of addsrc (issued before the compute loop, kept live)
    float addv[32];
    if (addsrc) {
#pragma unroll
        for (int i = 0; i < 32; i++) addv[i] = addsrc[base + (size_t)i * HW];
    } else {
#pragma unroll
        for (int i = 0; i < 32; i++) addv[i] = 0.f;
    }
    __builtin_amdgcn_sched_barrier(0);   // keep the loads issued up here

    float acc[32];
#pragma unroll
    for (int i = 0; i < 32; i++) acc[i] = 0.f;

    const float* wrh = wr + half * 32;   // uniform -> scalar loads below
#pragma unroll 1
    for (int kh = 0; kh < KS; kh++) {
#pragma unroll
        for (int kw = 0; kw < KS; kw++) {
            float v = t_s[(ty + kh) * DTW + tx + kw];
            const float* wk = wrh + (kh * KS + kw) * KC;
#pragma unroll
            for (int i = 0; i < 32; i++) acc[i] += v * wk[i];
        }
    }

#pragma unroll
    for (int g = 0; g < 4; g++) {
        frag8 vv;
#pragma unroll
        for (int j = 0; j < 8; j++) {
            int i = g * 8 + j;
            float v = acc[i] + bias[half * 32 + i];   // same assoc order as R6
            v += addv[i];                             // (+0.0f when no addsrc)
            v = (v > LAM) ? (v - LAM) : ((v < -LAM) ? (v + LAM) : 0.f);
            dst[base + (size_t)i * HW] = v;
            vv[j] = f2bf(v);
        }
        if (dst_t) {
            *(frag8*)(dst_t + ((size_t)s * HW + pix) * KC + half * 32 + g * 8) = vv;
        }
    }
}

// ---------------------------------------------------------------------------
// 64 -> 1 channel conv. If xsub != null, out = xsub - (conv+b); else conv+b.
// 32x8 tile; ic staged 4 planes/round, double-buffered LDS with register
// prefetch. Accumulation order (ic asc, kh, kw) identical -> bit-exact.
// ---------------------------------------------------------------------------
#define ICB   4
#define CHUNK (ICB * DTILE)   // 2128

__global__ __launch_bounds__(256) void conv64to1(
        const float* __restrict__ src,   // [31,64,HW]
        const float* __restrict__ w,     // [64*49] layout [ic][k]
        const float* __restrict__ bias,  // [1]
        const float* __restrict__ xsub,  // [31,HW] or nullptr
        float* __restrict__ dst)         // [31,HW]
{
    int s    = blockIdx.y;
    int tile = blockIdx.x;
    int tx = threadIdx.x & 31, ty = threadIdx.x >> 5;
    int w0 = (tile & 3) << 5, h0 = (tile >> 2) << 3;

    __shared__ float t_s[2][CHUNK];      // 17 KB

    // per-thread load slots: identical pattern every chunk, precompute once
    int  goff[9];
    bool okf[9];
#pragma unroll
    for (int r = 0; r < 9; r++) {
        int j = threadIdx.x + r * 256;
        if (j < CHUNK) {
            int plane = j / DTILE, p = j - plane * DTILE;
            int rr = p / DTW, cc = p - rr * DTW;
            int hh = h0 - 3 + rr, ww = w0 - 3 + cc;
            bool inb = (hh >= 0 && hh < IMG && ww >= 0 && ww < IMG);
            goff[r] = plane * HW + (inb ? (hh * IMG + ww) : 0);
            okf[r]  = inb;
        }
    }

    const float* sbase = src + (size_t)s * KC * HW;

    // stage chunk 0
    float ldv[9];
#pragma unroll
    for (int r = 0; r < 9; r++)
        if (threadIdx.x + r * 256 < CHUNK)
            ldv[r] = okf[r] ? sbase[goff[r]] : 0.f;
#pragma unroll
    for (int r = 0; r < 9; r++)
        if (threadIdx.x + r * 256 < CHUNK)
            t_s[0][threadIdx.x + r * 256] = ldv[r];

    float acc = 0.f;
    __syncthreads();

#pragma unroll 1
    for (int blk = 0; blk < 16; blk++) {
        int cur = blk & 1;
        // prefetch next chunk into regs (overlaps the compute below)
        if (blk < 15) {
            const float* nb = sbase + (size_t)(blk + 1) * ICB * HW;
#pragma unroll
            for (int r = 0; r < 9; r++)
                if (threadIdx.x + r * 256 < CHUNK)
                    ldv[r] = okf[r] ? nb[goff[r]] : 0.f;
        }
        __builtin_amdgcn_sched_barrier(0);
        // compute 4 planes of this chunk
#pragma unroll
        for (int pl = 0; pl < ICB; pl++) {
            int ic = blk * ICB + pl;
            const float* wk = w + ic * KK;
            const float* ts = &t_s[cur][pl * DTILE];
#pragma unroll 1
            for (int kh = 0; kh < KS; kh++) {
#pragma unroll
                for (int kw = 0; kw < KS; kw++)
                    acc += ts[(ty + kh) * DTW + tx + kw] * wk[kh * KS + kw];
            }
        }
        __syncthreads();
        if (blk < 15) {
#pragma unroll
            for (int r = 0; r < 9; r++)
                if (threadIdx.x + r * 256 < CHUNK)
                    t_s[cur ^ 1][threadIdx.x + r * 256] = ldv[r];
            __syncthreads();
        }
    }

    float v = acc + bias[0];
    int pix = (h0 + ty) * IMG + (w0 + tx);
    if (xsub) v = xsub[(size_t)s * HW + pix] - v;
    dst[(size_t)s * HW + pix] = v;
}

// ---------------------------------------------------------------------------
// conv_z as bf16 MFMA shift-GEMM: zpre[s][oc][px] = sum_{ic,kh,kw} ...
// Block: 256 thr (4 waves) = 16x16 pixel tile x 64 oc, all 49 taps.
// ks-SPLIT: two passes over the taps; pass p stages only ic [p*32,p*32+32)
//   -> LDS 30,976 B -> 4 blocks/CU; __launch_bounds__(256,4) -> 4 waves/SIMD.
// A tile: plane-major (4 planes x 484 px, stride 7744 B), conflict-light b128.
// K-loop: kh rolled (7 iters), kw unrolled -> ~1.7 KB body, I-cache hot.
// B taps: direct-from-global (L2-resident), no LDS, no barriers in tap loop.
// Epilogue: fused BN partial sums via q-lane shfl + atomicAdd.
// ---------------------------------------------------------------------------
__global__ __launch_bounds__(256, 4) void conv_z_mfma(
        const short* __restrict__ srcT,  // [31,HW,64] bf16 (tmp_t)
        const short* __restrict__ wfrag, // per-layer B-frag buffer (bf16 bits)
        const float* __restrict__ bias,  // [64]
        float* __restrict__ dst,         // [31,64,HW] (zpre)
        float* __restrict__ pstats)      // [31*64][2] partial sums (pre-zeroed)
{
    __shared__ __align__(16) short a_s[4 * PLSTRIDE]; // 30,976 B

    int s    = blockIdx.y;
    int tile = blockIdx.x;
    int h0 = (tile >> 3) << 4, w0 = (tile & 7) << 4;
    int tid  = threadIdx.x;
    int wave = tid >> 6, lane = tid & 63;
    int q = lane >> 4, m = lane & 15;

    const short* tsrc = srcT + (size_t)s * HW * KC;

    facc4 acc[4][4];
#pragma unroll
    for (int i = 0; i < 4; i++)
#pragma unroll
        for (int j = 0; j < 4; j++)
            acc[i][j] = (facc4){0.f, 0.f, 0.f, 0.f};

#pragma unroll 1
    for (int pass = 0; pass < 2; ++pass) {
        if (pass) __syncthreads();       // all pass-0 reads done before overwrite

        // ---- stage ic half [pass*32, pass*32+32) -> planes 0..3 (b128 only)
#pragma unroll
        for (int rep = 0; rep < 2; rep++) {
            int p = tid + rep * 256;
            if (p < 484) {
                int r = p / 22, c = p - r * 22;
                int hh = h0 - 3 + r, ww = w0 - 3 + c;
                bool ok = (hh >= 0 && hh < IMG && ww >= 0 && ww < IMG);
                const short* px = tsrc + ((size_t)(ok ? (hh * IMG + ww) : 0) << 6)
                                       + (pass << 5);
                short* dp = a_s + p * 8;
#pragma unroll
                for (int c4 = 0; c4 < 4; c4++) {
                    frag8 v;
                    if (ok) v = *(const frag8*)(px + (c4 << 3));
                    else    v = (frag8)(short)0;
                    *(frag8*)(dp + c4 * PLSTRIDE) = v;
                }
            }
        }
        __syncthreads();

        // rolling per-lane bases: A row (kh) base and B row-of-taps base
        const short* arow = a_s + q * PLSTRIDE + (wave * 4 * 22 + m) * 8;
        const frag8* brow = (const frag8*)wfrag + (pass * 4) * 64 + lane;

#pragma unroll 1
        for (int kh = 0; kh < 7; ++kh) {
#pragma unroll
            for (int kw = 0; kw < 7; ++kw) {
                frag8 b0 = brow[kw * 512 + 0 * 64];
                frag8 b1 = brow[kw * 512 + 1 * 64];
                frag8 b2 = brow[kw * 512 + 2 * 64];
                frag8 b3 = brow[kw * 512 + 3 * 64];
                frag8 a0 = *(const frag8*)(arow + (0 * 22 + kw) * 8);
                frag8 a1 = *(const frag8*)(arow + (1 * 22 + kw) * 8);
                frag8 a2 = *(const frag8*)(arow + (2 * 22 + kw) * 8);
                frag8 a3 = *(const frag8*)(arow + (3 * 22 + kw) * 8);
                acc[0][0] = __builtin_amdgcn_mfma_f32_16x16x32_bf16(a0, b0, acc[0][0], 0, 0, 0);
                acc[0][1] = __builtin_amdgcn_mfma_f32_16x16x32_bf16(a0, b1, acc[0][1], 0, 0, 0);
                acc[0][2] = __builtin_amdgcn_mfma_f32_16x16x32_bf16(a0, b2, acc[0][2], 0, 0, 0);
                acc[0][3] = __builtin_amdgcn_mfma_f32_16x16x32_bf16(a0, b3, acc[0][3], 0, 0, 0);
                acc[1][0] = __builtin_amdgcn_mfma_f32_16x16x32_bf16(a1, b0, acc[1][0], 0, 0, 0);
                acc[1][1] = __builtin_amdgcn_mfma_f32_16x16x32_bf16(a1, b1, acc[1][1], 0, 0, 0);
                acc[1][2] = __builtin_amdgcn_mfma_f32_16x16x32_bf16(a1, b2, acc[1][2], 0, 0, 0);
                acc[1][3] = __builtin_amdgcn_mfma_f32_16x16x32_bf16(a1, b3, acc[1][3], 0, 0, 0);
                acc[2][0] = __builtin_amdgcn_mfma_f32_16x16x32_bf16(a2, b0, acc[2][0], 0, 0, 0);
                acc[2][1] = __builtin_amdgcn_mfma_f32_16x16x32_bf16(a2, b1, acc[2][1], 0, 0, 0);
                acc[2][2] = __builtin_amdgcn_mfma_f32_16x16x32_bf16(a2, b2, acc[2][2], 0, 0, 0);
                acc[2][3] = __builtin_amdgcn_mfma_f32_16x16x32_bf16(a2, b3, acc[2][3], 0, 0, 0);
                acc[3][0] = __builtin_amdgcn_mfma_f32_16x16x32_bf16(a3, b0, acc[3][0], 0, 0, 0);
                acc[3][1] = __builtin_amdgcn_mfma_f32_16x16x32_bf16(a3, b1, acc[3][1], 0, 0, 0);
                acc[3][2] = __builtin_amdgcn_mfma_f32_16x16x32_bf16(a3, b2, acc[3][2], 0, 0, 0);
                acc[3][3] = __builtin_amdgcn_mfma_f32_16x16x32_bf16(a3, b3, acc[3][3], 0, 0, 0);
            }
            arow += 22 * 8;     // next kh row of the A tile
            brow += 7 * 512;    // next row of 7 taps in wz_frag
        }
    }

    // ---- epilogue: D layout col(oc-part)=lane&15, row(px col)=q*4+reg
    //      + fused BN partial sums (per oc: reduce over q-lanes, atomicAdd)
    int prow = h0 + wave * 4;
#pragma unroll
    for (int og = 0; og < 4; og++) {
        int oc = og * 16 + m;
        float bb = bias[oc];
        float s1 = 0.f, s2 = 0.f;
#pragma unroll
        for (int pg = 0; pg < 4; pg++) {
            float* dp = dst + ((size_t)s * KC + oc) * HW
                            + (size_t)(prow + pg) * IMG + w0 + q * 4;
            float4 v;
            v.x = acc[pg][og][0] + bb;
            v.y = acc[pg][og][1] + bb;
            v.z = acc[pg][og][2] + bb;
            v.w = acc[pg][og][3] + bb;
            s1 += v.x + v.y + v.z + v.w;
            s2 += v.x * v.x + v.y * v.y + v.z * v.z + v.w * v.w;
            *(float4*)dp = v;
        }
        // reduce over the 4 q-lanes sharing this oc (lane bits 4,5)
        s1 += __shfl_xor(s1, 16, 64); s2 += __shfl_xor(s2, 16, 64);
        s1 += __shfl_xor(s1, 32, 64); s2 += __shfl_xor(s2, 32, 64);
        if (q == 0) {
            atomicAdd(&pstats[(s * KC + oc) * 2],     s1);
            atomicAdd(&pstats[(s * KC + oc) * 2 + 1], s2);
        }
    }
}

// ---------------------------------------------------------------------------
// Finalize BN stats from fused partial sums; re-zero pstats for next iter.
// ---------------------------------------------------------------------------
__global__ __launch_bounds__(64) void bn_finalize(
        float* __restrict__ pstats,   // [31*64][2] partial sums
        float* __restrict__ stats)    // [31*64][2] -> (mu, rsqrt(var+eps))
{
    int i = blockIdx.x * 64 + threadIdx.x;
    if (i < S31 * KC) {
        float s1 = pstats[i * 2], s2 = pstats[i * 2 + 1];
        pstats[i * 2] = 0.f;
        pstats[i * 2 + 1] = 0.f;
        float mu  = s1 * (1.f / HW);
        float var = s2 * (1.f / HW) - mu * mu;
        if (var < 0.f) var = 0.f;
        stats[i * 2]     = mu;
        stats[i * 2 + 1] = rsqrtf(var + BNEPS);
    }
}

// ---------------------------------------------------------------------------
// Directional gated band scan: each thread owns one (c,h,w), walks 31 bands.
// ---------------------------------------------------------------------------
__global__ __launch_bounds__(256) void band_scan(
        const float* __restrict__ tmp,   // [31,64,HW]
        const float* __restrict__ zpre,  // [31,64,HW]
        const float* __restrict__ stats, // [31*64][2]
        const float* __restrict__ gamma, // [64]
        const float* __restrict__ beta,  // [64]
        float* __restrict__ csc,         // [31,64,HW]
        int fwd)
{
    int idx = blockIdx.x * 256 + threadIdx.x;  // 0 .. 64*HW-1
    int c = idx >> 14;
    float g = gamma[c], be = beta[c];
    float prev = 0.f;
    for (int step = 0; step < S31; step++) {
        int s = fwd ? step : (S31 - 1 - step);
        size_t off = (size_t)s * KC * HW + idx;
        float t  = tmp[off];
        float zp = zpre[off];
        float mu = stats[(s * KC + c) * 2];
        float rs = stats[(s * KC + c) * 2 + 1];
        float zn = (zp - mu) * rs * g + be;
        float z  = 1.f / (1.f + expf(-zn));
        float cur = (step == 0) ? t : (z * prev + (1.f - z) * t);
        csc[off] = cur;
        prev = cur;
    }
}

// ---------------------------------------------------------------------------
extern "C" void kernel_launch(void* const* d_in, const int* in_sizes, int n_in,
                              void* d_out, int out_size, void* d_ws, size_t ws_size,
                              hipStream_t stream) {
    const float* x      = (const float*)d_in[0];   // [1,31,128,128]
    const float* W_fe   = (const float*)d_in[1];
    const float* b_fe   = (const float*)d_in[2];
    const float* W_enc  = (const float*)d_in[3];
    const float* b_enc  = (const float*)d_in[4];
    const float* W_dec  = (const float*)d_in[5];
    const float* b_dec  = (const float*)d_in[6];
    const float* W_last = (const float*)d_in[7];
    const float* b_last = (const float*)d_in[8];
    const float* W_z    = (const float*)d_in[9];
    const float* b_z    = (const float*)d_in[10];
    const float* bn_g   = (const float*)d_in[11];
    const float* bn_b   = (const float*)d_in[12];

    float* out     = (float*)d_out;
    float* csc     = out;                               // [31,1,64,128,128]
    float* outputs = out + (size_t)S31 * KC * HW;       // [1,31,128,128]

    char* ws = (char*)d_ws;
    float* tmp     = (float*)ws; ws += (size_t)S31 * KC * HW * 4;
    float* zpre    = (float*)ws; ws += (size_t)S31 * KC * HW * 4;
    float* res     = (float*)ws; ws += (size_t)S31 * HW * 4;
    float* stats   = (float*)ws; ws += (size_t)S31 * KC * 2 * 4;
    float* pstats  = (float*)ws; ws += (size_t)S31 * KC * 2 * 4;
    short* wz_frag = (short*)ws; ws += (size_t)3 * KK * 4096 * 2;  // bf16 frags
    float* wenc_r  = (float*)ws; ws += (size_t)3 * KK * KC * 4;
    float* wfe_r   = (float*)ws; ws += (size_t)KK * KC * 4;
    short* tmp_t   = (short*)ws; ws += (size_t)S31 * HW * KC * 2;  // bf16 pix-major

    // 1) weight reorder / frag-swizzle (+ zero pstats)
    {
        int total = 3 * KK * 4096 + 3 * KK * KC + KK * KC + 2 * S31 * KC;
        reorder_weights<<<(total + 255) / 256, 256, 0, stream>>>(
            W_z, W_enc, W_fe, wz_frag, wenc_r, wfe_r, pstats);
    }

    dim3 gconv(64, S31);     // conv64to1 / conv_z grids
    dim3 gconv2(128, S31);   // conv1to64: 64 tiles x 2 oc-halves

    // 2) csc = softshrink(conv_fe(x))
    conv1to64<<<gconv2, 256, 0, stream>>>(x, wfe_r, b_fe, nullptr, csc, nullptr);

    for (int it = 0; it < 3; it++) {
        int lyr = it;
        // res = x - (conv_dec(csc) + b_dec)
        conv64to1<<<gconv, 256, 0, stream>>>(
            csc, W_dec + (size_t)lyr * KC * KK, b_dec + lyr, x, res);
        // tmp = softshrink(csc + conv_enc(res) + b_enc)  (+ bf16 pix-major copy)
        conv1to64<<<gconv2, 256, 0, stream>>>(
            res, wenc_r + (size_t)lyr * KK * KC, b_enc + (size_t)lyr * KC, csc,
            tmp, tmp_t);
        // zpre = conv_z(tmp) + b_z   (bf16 MFMA shift-GEMM, ks-split LDS,
        //                             4 blocks/CU + 4 waves/SIMD, fused BN)
        conv_z_mfma<<<gconv, 256, 0, stream>>>(
            tmp_t, wz_frag + (size_t)lyr * KK * 4096, b_z + (size_t)lyr * KC,
            zpre, pstats);
        // BN finalize (also re-zeroes pstats for the next iteration)
        bn_finalize<<<S31, 64, 0, stream>>>(pstats, stats);
        // gated directional scan -> csc
        band_scan<<<(KC * HW) / 256, 256, 0, stream>>>(
            tmp, zpre, stats, bn_g + (size_t)lyr * KC, bn_b + (size_t)lyr * KC,
            csc, (it % 2 == 0) ? 1 : 0);
    }

    // 3) outputs = conv_last(csc) + b_last
    conv64to1<<<gconv, 256, 0, stream>>>(csc, W_last, b_last, nullptr, outputs);
}